// Round 6
// baseline (792.788 us; speedup 1.0000x reference)
//
#include <hip/hip_runtime.h>
#include <math.h>

#define NODES 100000
#define EDGES 1600000
#define INDIM 128
#define HDIM 64
#define SCAN_CHUNK 1024

typedef __attribute__((ext_vector_type(8))) short short8;
typedef __attribute__((ext_vector_type(4))) float floatx4;

__device__ __forceinline__ float wave_sum(float x) {
#pragma unroll
  for (int o = 32; o > 0; o >>= 1) x += __shfl_xor(x, o, 64);
  return x;
}

// bf16 <-> fp32 without relying on __hip_bfloat16 struct internals.
// RNE rounding, matches hardware v_cvt semantics for finite values.
__device__ __forceinline__ short f2bf(float f) {
  union { float f; unsigned u; } v;
  v.f = f;
  unsigned r = 0x7fffu + ((v.u >> 16) & 1u);
  return (short)((v.u + r) >> 16);
}
__device__ __forceinline__ float bf2f(short s) {
  union { unsigned u; float f; } v;
  v.u = ((unsigned)(unsigned short)s) << 16;
  return v.f;
}

// ---------- degree count ----------
__global__ void k_count(const int* __restrict__ dst, int* __restrict__ deg) {
  int e = blockIdx.x * blockDim.x + threadIdx.x;
  if (e < EDGES) atomicAdd(&deg[dst[e]], 1);
}

__global__ void k_dinv(const int* __restrict__ deg, float* __restrict__ dinv) {
  int n = blockIdx.x * blockDim.x + threadIdx.x;
  if (n < NODES) dinv[n] = rsqrtf((float)deg[n] + 1.0f);
}

// ---------- scan (3-phase exclusive prefix over deg) ----------
__global__ void k_scan1(const int* __restrict__ deg, int* __restrict__ part) {
  __shared__ int sw[4];
  int b = blockIdx.x, t = threadIdx.x;
  int base = b * SCAN_CHUNK;
  int s = 0;
#pragma unroll
  for (int j = 0; j < 4; ++j) {
    int i = base + t * 4 + j;
    if (i < NODES) s += deg[i];
  }
  for (int o = 32; o > 0; o >>= 1) s += __shfl_xor(s, o, 64);
  if ((t & 63) == 0) sw[t >> 6] = s;
  __syncthreads();
  if (t == 0) part[b] = sw[0] + sw[1] + sw[2] + sw[3];
}

__global__ void k_scan2(int* part, int nb) {
  __shared__ int sm[128];
  int t = threadIdx.x;
  int v = (t < nb) ? part[t] : 0;
  sm[t] = v;
  __syncthreads();
  for (int o = 1; o < 128; o <<= 1) {
    int u = (t >= o) ? sm[t - o] : 0;
    __syncthreads();
    sm[t] += u;
    __syncthreads();
  }
  if (t < nb) part[t] = sm[t] - v;  // exclusive
}

__global__ void k_scan3(const int* __restrict__ deg, const int* __restrict__ part,
                        int* __restrict__ rowptr, int* __restrict__ cursor) {
  __shared__ int wtot[4];
  int b = blockIdx.x, t = threadIdx.x;
  int lane = t & 63, wid = t >> 6;
  int base = b * SCAN_CHUNK;
  int d[4];
  int s = 0;
#pragma unroll
  for (int j = 0; j < 4; ++j) {
    int i = base + t * 4 + j;
    d[j] = (i < NODES) ? deg[i] : 0;
    s += d[j];
  }
  int inc = s;
#pragma unroll
  for (int o = 1; o < 64; o <<= 1) {
    int u = __shfl_up(inc, o, 64);
    if (lane >= o) inc += u;
  }
  if (lane == 63) wtot[wid] = inc;
  __syncthreads();
  int wpre = 0;
  for (int w = 0; w < wid; ++w) wpre += wtot[w];
  int off = part[b] + wpre + inc - s;
#pragma unroll
  for (int j = 0; j < 4; ++j) {
    int i = base + t * 4 + j;
    if (i < NODES) { rowptr[i] = off; cursor[i] = off; off += d[j]; }
  }
  if (b == 0 && t == 0) rowptr[NODES] = EDGES;
}

__global__ void k_fill(const int* __restrict__ src, const int* __restrict__ dst,
                       int* __restrict__ cursor, int* __restrict__ csr) {
  int e = blockIdx.x * blockDim.x + threadIdx.x;
  if (e < EDGES) {
    int p = atomicAdd(&cursor[dst[e]], 1);
    csr[p] = src[e];
  }
}

// ---------- GEMM (fp32 activations): [N,K] fp32 @ [K,64] fp32 -> [N,64] bf16 ----------
template <int K>
__global__ __launch_bounds__(256) void k_gemm_f32(const float* __restrict__ x,
                                                  const float* __restrict__ W,
                                                  short* __restrict__ h) {
  constexpr int KP = K + 8;  // row stride (K+8)*2B = multiple of 16 -> aligned b128 reads
  __shared__ short wt[64 * KP];
  for (int idx = threadIdx.x; idx < K * 64; idx += 256) {
    int k = idx >> 6, n = idx & 63;
    wt[n * KP + k] = f2bf(W[idx]);  // W^T staged as bf16
  }
  __syncthreads();
  int wid = threadIdx.x >> 6, lane = threadIdx.x & 63;
  int tile = blockIdx.x * 4 + wid;
  if (tile * 16 >= NODES) return;
  int m = lane & 15, q = lane >> 4;

  // B fragment: B[n = lane&15][k = q*8 + j]
  short8 bfr[4][K / 32];
#pragma unroll
  for (int ct = 0; ct < 4; ++ct)
#pragma unroll
    for (int ks = 0; ks < K / 32; ++ks)
      bfr[ct][ks] = *reinterpret_cast<const short8*>(&wt[(ct * 16 + m) * KP + ks * 32 + q * 8]);

  floatx4 acc[4];
#pragma unroll
  for (int ct = 0; ct < 4; ++ct) acc[ct] = {0.f, 0.f, 0.f, 0.f};
  int r0 = tile * 16;
#pragma unroll
  for (int ks = 0; ks < K / 32; ++ks) {
    // A fragment: A[m = lane&15][k = q*8 + j] -- 8 fp32 -> bf16
    const float* xp = &x[(size_t)(r0 + m) * K + ks * 32 + q * 8];
    floatx4 a0 = *reinterpret_cast<const floatx4*>(xp);
    floatx4 a1 = *reinterpret_cast<const floatx4*>(xp + 4);
    short8 af;
#pragma unroll
    for (int j = 0; j < 4; ++j) { af[j] = f2bf(a0[j]); af[4 + j] = f2bf(a1[j]); }
#pragma unroll
    for (int ct = 0; ct < 4; ++ct)
      acc[ct] = __builtin_amdgcn_mfma_f32_16x16x32_bf16(af, bfr[ct][ks], acc[ct], 0, 0, 0);
  }
  // C/D: col = lane&15, row = (lane>>4)*4 + reg   [measured m89/m91]
#pragma unroll
  for (int ct = 0; ct < 4; ++ct)
#pragma unroll
    for (int r = 0; r < 4; ++r) {
      int row = r0 + q * 4 + r, col = ct * 16 + m;
      h[row * 64 + col] = f2bf(acc[ct][r]);
    }
}

// ---------- GEMM (bf16 activations): [N,64] bf16 @ [64,64] fp32 -> [N,64] bf16 ----------
__global__ __launch_bounds__(256) void k_gemm_bf(const short* __restrict__ x,
                                                 const float* __restrict__ W,
                                                 short* __restrict__ h) {
  constexpr int K = 64, KP = K + 8;
  __shared__ short wt[64 * KP];
  for (int idx = threadIdx.x; idx < K * 64; idx += 256) {
    int k = idx >> 6, n = idx & 63;
    wt[n * KP + k] = f2bf(W[idx]);
  }
  __syncthreads();
  int wid = threadIdx.x >> 6, lane = threadIdx.x & 63;
  int tile = blockIdx.x * 4 + wid;
  if (tile * 16 >= NODES) return;
  int m = lane & 15, q = lane >> 4;

  short8 bfr[4][2];
#pragma unroll
  for (int ct = 0; ct < 4; ++ct)
#pragma unroll
    for (int ks = 0; ks < 2; ++ks)
      bfr[ct][ks] = *reinterpret_cast<const short8*>(&wt[(ct * 16 + m) * KP + ks * 32 + q * 8]);

  floatx4 acc[4];
#pragma unroll
  for (int ct = 0; ct < 4; ++ct) acc[ct] = {0.f, 0.f, 0.f, 0.f};
  int r0 = tile * 16;
#pragma unroll
  for (int ks = 0; ks < 2; ++ks) {
    short8 af = *reinterpret_cast<const short8*>(&x[(size_t)(r0 + m) * K + ks * 32 + q * 8]);
#pragma unroll
    for (int ct = 0; ct < 4; ++ct)
      acc[ct] = __builtin_amdgcn_mfma_f32_16x16x32_bf16(af, bfr[ct][ks], acc[ct], 0, 0, 0);
  }
#pragma unroll
  for (int ct = 0; ct < 4; ++ct)
#pragma unroll
    for (int r = 0; r < 4; ++r) {
      int row = r0 + q * 4 + r, col = ct * 16 + m;
      h[row * 64 + col] = f2bf(acc[ct][r]);
    }
}

// ---------- fused aggregate + bias + LayerNorm + GELU (+ optional head) ----------
template <int FINAL>
__global__ __launch_bounds__(256) void k_agg(const short* __restrict__ h,
                                             const float* __restrict__ dinv,
                                             const int* __restrict__ rowptr,
                                             const int* __restrict__ csr,
                                             const float* __restrict__ bias,
                                             const float* __restrict__ gam,
                                             const float* __restrict__ bet,
                                             const float* __restrict__ Wh,
                                             const float* __restrict__ bh,
                                             void* __restrict__ out) {
  int wid = threadIdx.x >> 6, lane = threadIdx.x & 63;
  int n = blockIdx.x * 4 + wid;
  if (n >= NODES) return;
  float dn = dinv[n];
  float acc = bf2f(h[n * 64 + lane]) * dn * dn;  // self-loop
  int e0 = rowptr[n], e1 = rowptr[n + 1];
  for (int e = e0; e < e1; ++e) {
    int s = csr[e];
    acc += bf2f(h[s * 64 + lane]) * (dinv[s] * dn);
  }
  acc += bias[lane];
  float mu = wave_sum(acc) * (1.0f / 64.0f);
  float d = acc - mu;
  float var = wave_sum(d * d) * (1.0f / 64.0f);
  float v = d * rsqrtf(var + 1e-5f) * gam[lane] + bet[lane];
  float u = 0.5f * v * (1.0f + erff(v * 0.70710678118654752f));  // exact GELU
  if (FINAL) {
    float p = wave_sum(u * Wh[lane]);
    if (lane == 0) ((float*)out)[n] = p + bh[0];
  } else {
    ((short*)out)[n * 64 + lane] = f2bf(u);
  }
}

extern "C" void kernel_launch(void* const* d_in, const int* in_sizes, int n_in,
                              void* d_out, int out_size, void* d_ws, size_t ws_size,
                              hipStream_t stream) {
  const float* x  = (const float*)d_in[0];
  const int* ei   = (const int*)d_in[1];
  const float* W1 = (const float*)d_in[2];
  const float* b1 = (const float*)d_in[3];
  const float* g1 = (const float*)d_in[4];
  const float* be1= (const float*)d_in[5];
  const float* W2 = (const float*)d_in[6];
  const float* b2 = (const float*)d_in[7];
  const float* g2 = (const float*)d_in[8];
  const float* be2= (const float*)d_in[9];
  const float* W3 = (const float*)d_in[10];
  const float* b3 = (const float*)d_in[11];
  const float* g3 = (const float*)d_in[12];
  const float* be3= (const float*)d_in[13];
  const float* Wh = (const float*)d_in[14];
  const float* bh = (const float*)d_in[15];
  const int* srcp = ei;
  const int* dstp = ei + EDGES;

  char* ws = (char*)d_ws;
  size_t off = 0;
  auto take = [&](size_t bytes) {
    char* p = ws + off;
    off = (off + bytes + 255) & ~(size_t)255;
    return p;
  };
  int* deg    = (int*)take((size_t)NODES * 4);
  float* dinv = (float*)take((size_t)NODES * 4);
  int* rowptr = (int*)take((size_t)(NODES + 1) * 4);
  int* cursor = (int*)take((size_t)NODES * 4);
  int* part   = (int*)take(512);
  int* csr    = (int*)take((size_t)EDGES * 4);
  short* h    = (short*)take((size_t)NODES * 64 * 2);
  short* xb   = (short*)take((size_t)NODES * 64 * 2);

  (void)hipMemsetAsync(deg, 0, (size_t)NODES * 4, stream);
  int nb = (NODES + SCAN_CHUNK - 1) / SCAN_CHUNK;  // 98
  k_count<<<(EDGES + 255) / 256, 256, 0, stream>>>(dstp, deg);
  k_dinv<<<(NODES + 255) / 256, 256, 0, stream>>>(deg, dinv);
  k_scan1<<<nb, 256, 0, stream>>>(deg, part);
  k_scan2<<<1, 128, 0, stream>>>(part, nb);
  k_scan3<<<nb, 256, 0, stream>>>(deg, part, rowptr, cursor);
  k_fill<<<(EDGES + 255) / 256, 256, 0, stream>>>(srcp, dstp, cursor, csr);

  int gemm_grid = (NODES / 16 + 3) / 4;  // 1563 blocks x 4 waves
  k_gemm_f32<128><<<gemm_grid, 256, 0, stream>>>(x, W1, h);
  k_agg<0><<<NODES / 4, 256, 0, stream>>>(h, dinv, rowptr, csr, b1, g1, be1, nullptr, nullptr, xb);
  k_gemm_bf<<<gemm_grid, 256, 0, stream>>>(xb, W2, h);
  k_agg<0><<<NODES / 4, 256, 0, stream>>>(h, dinv, rowptr, csr, b2, g2, be2, nullptr, nullptr, xb);
  k_gemm_bf<<<gemm_grid, 256, 0, stream>>>(xb, W3, h);
  k_agg<1><<<NODES / 4, 256, 0, stream>>>(h, dinv, rowptr, csr, b3, g3, be3, Wh, bh, d_out);
}

// Round 7
// 499.860 us; speedup vs baseline: 1.5860x; 1.5860x over previous
//
#include <hip/hip_runtime.h>
#include <math.h>

#define NODES 100000
#define EDGES 1600000
#define INDIM 128
#define HDIM 64
#define SCAN_CHUNK 1024

typedef __attribute__((ext_vector_type(8))) short short8;
typedef __attribute__((ext_vector_type(4))) float floatx4;

__device__ __forceinline__ float wave_sum(float x) {
#pragma unroll
  for (int o = 32; o > 0; o >>= 1) x += __shfl_xor(x, o, 64);
  return x;
}

// bf16 <-> fp32 without relying on __hip_bfloat16 struct internals (RNE).
__device__ __forceinline__ short f2bf(float f) {
  union { float f; unsigned u; } v;
  v.f = f;
  unsigned r = 0x7fffu + ((v.u >> 16) & 1u);
  return (short)((v.u + r) >> 16);
}
__device__ __forceinline__ float bf2f(short s) {
  union { unsigned u; float f; } v;
  v.u = ((unsigned)(unsigned short)s) << 16;
  return v.f;
}

// ---------- degree count ----------
__global__ void k_count(const int* __restrict__ dst, int* __restrict__ deg) {
  int e = blockIdx.x * blockDim.x + threadIdx.x;
  if (e < EDGES) atomicAdd(&deg[dst[e]], 1);
}

__global__ void k_dinv(const int* __restrict__ deg, float* __restrict__ dinv) {
  int n = blockIdx.x * blockDim.x + threadIdx.x;
  if (n < NODES) dinv[n] = rsqrtf((float)deg[n] + 1.0f);
}

// ---------- scan (3-phase exclusive prefix over deg) ----------
__global__ void k_scan1(const int* __restrict__ deg, int* __restrict__ part) {
  __shared__ int sw[4];
  int b = blockIdx.x, t = threadIdx.x;
  int base = b * SCAN_CHUNK;
  int s = 0;
#pragma unroll
  for (int j = 0; j < 4; ++j) {
    int i = base + t * 4 + j;
    if (i < NODES) s += deg[i];
  }
  for (int o = 32; o > 0; o >>= 1) s += __shfl_xor(s, o, 64);
  if ((t & 63) == 0) sw[t >> 6] = s;
  __syncthreads();
  if (t == 0) part[b] = sw[0] + sw[1] + sw[2] + sw[3];
}

__global__ void k_scan2(int* part, int nb) {
  __shared__ int sm[128];
  int t = threadIdx.x;
  int v = (t < nb) ? part[t] : 0;
  sm[t] = v;
  __syncthreads();
  for (int o = 1; o < 128; o <<= 1) {
    int u = (t >= o) ? sm[t - o] : 0;
    __syncthreads();
    sm[t] += u;
    __syncthreads();
  }
  if (t < nb) part[t] = sm[t] - v;  // exclusive
}

__global__ void k_scan3(const int* __restrict__ deg, const int* __restrict__ part,
                        int* __restrict__ rowptr, int* __restrict__ cursor) {
  __shared__ int wtot[4];
  int b = blockIdx.x, t = threadIdx.x;
  int lane = t & 63, wid = t >> 6;
  int base = b * SCAN_CHUNK;
  int d[4];
  int s = 0;
#pragma unroll
  for (int j = 0; j < 4; ++j) {
    int i = base + t * 4 + j;
    d[j] = (i < NODES) ? deg[i] : 0;
    s += d[j];
  }
  int inc = s;
#pragma unroll
  for (int o = 1; o < 64; o <<= 1) {
    int u = __shfl_up(inc, o, 64);
    if (lane >= o) inc += u;
  }
  if (lane == 63) wtot[wid] = inc;
  __syncthreads();
  int wpre = 0;
  for (int w = 0; w < wid; ++w) wpre += wtot[w];
  int off = part[b] + wpre + inc - s;
#pragma unroll
  for (int j = 0; j < 4; ++j) {
    int i = base + t * 4 + j;
    if (i < NODES) { rowptr[i] = off; cursor[i] = off; off += d[j]; }
  }
  if (b == 0 && t == 0) rowptr[NODES] = EDGES;
}

__global__ void k_fill(const int* __restrict__ src, const int* __restrict__ dst,
                       int* __restrict__ cursor, int* __restrict__ csr) {
  int e = blockIdx.x * blockDim.x + threadIdx.x;
  if (e < EDGES) {
    int p = atomicAdd(&cursor[dst[e]], 1);
    csr[p] = src[e];
  }
}

// ---------- GEMM (fp32 acts): [N,K] fp32 @ [K,64] fp32 -> hs = (x@W)*dinv[row], bf16 ----------
template <int K>
__global__ __launch_bounds__(256) void k_gemm_f32(const float* __restrict__ x,
                                                  const float* __restrict__ W,
                                                  const float* __restrict__ dinv,
                                                  short* __restrict__ hs) {
  constexpr int KP = K + 8;
  __shared__ short wt[64 * KP];
  for (int idx = threadIdx.x; idx < K * 64; idx += 256) {
    int k = idx >> 6, n = idx & 63;
    wt[n * KP + k] = f2bf(W[idx]);  // W^T staged as bf16
  }
  __syncthreads();
  int wid = threadIdx.x >> 6, lane = threadIdx.x & 63;
  int tile = blockIdx.x * 4 + wid;
  if (tile * 16 >= NODES) return;
  int m = lane & 15, q = lane >> 4;

  short8 bfr[4][K / 32];
#pragma unroll
  for (int ct = 0; ct < 4; ++ct)
#pragma unroll
    for (int ks = 0; ks < K / 32; ++ks)
      bfr[ct][ks] = *reinterpret_cast<const short8*>(&wt[(ct * 16 + m) * KP + ks * 32 + q * 8]);

  floatx4 acc[4];
#pragma unroll
  for (int ct = 0; ct < 4; ++ct) acc[ct] = {0.f, 0.f, 0.f, 0.f};
  int r0 = tile * 16;
#pragma unroll
  for (int ks = 0; ks < K / 32; ++ks) {
    const float* xp = &x[(size_t)(r0 + m) * K + ks * 32 + q * 8];
    floatx4 a0 = *reinterpret_cast<const floatx4*>(xp);
    floatx4 a1 = *reinterpret_cast<const floatx4*>(xp + 4);
    short8 af;
#pragma unroll
    for (int j = 0; j < 4; ++j) { af[j] = f2bf(a0[j]); af[4 + j] = f2bf(a1[j]); }
#pragma unroll
    for (int ct = 0; ct < 4; ++ct)
      acc[ct] = __builtin_amdgcn_mfma_f32_16x16x32_bf16(af, bfr[ct][ks], acc[ct], 0, 0, 0);
  }
  // C/D: col = lane&15, row = (lane>>4)*4 + reg   [measured m89/m91]
  float dv[4];
#pragma unroll
  for (int r = 0; r < 4; ++r) dv[r] = dinv[r0 + q * 4 + r];
#pragma unroll
  for (int ct = 0; ct < 4; ++ct)
#pragma unroll
    for (int r = 0; r < 4; ++r) {
      int row = r0 + q * 4 + r, col = ct * 16 + m;
      hs[row * 64 + col] = f2bf(acc[ct][r] * dv[r]);
    }
}

// ---------- GEMM (bf16 acts): [N,64] bf16 @ [64,64] fp32 -> hs bf16 (dinv-prescaled) ----------
__global__ __launch_bounds__(256) void k_gemm_bf(const short* __restrict__ x,
                                                 const float* __restrict__ W,
                                                 const float* __restrict__ dinv,
                                                 short* __restrict__ hs) {
  constexpr int K = 64, KP = K + 8;
  __shared__ short wt[64 * KP];
  for (int idx = threadIdx.x; idx < K * 64; idx += 256) {
    int k = idx >> 6, n = idx & 63;
    wt[n * KP + k] = f2bf(W[idx]);
  }
  __syncthreads();
  int wid = threadIdx.x >> 6, lane = threadIdx.x & 63;
  int tile = blockIdx.x * 4 + wid;
  if (tile * 16 >= NODES) return;
  int m = lane & 15, q = lane >> 4;

  short8 bfr[4][2];
#pragma unroll
  for (int ct = 0; ct < 4; ++ct)
#pragma unroll
    for (int ks = 0; ks < 2; ++ks)
      bfr[ct][ks] = *reinterpret_cast<const short8*>(&wt[(ct * 16 + m) * KP + ks * 32 + q * 8]);

  floatx4 acc[4];
#pragma unroll
  for (int ct = 0; ct < 4; ++ct) acc[ct] = {0.f, 0.f, 0.f, 0.f};
  int r0 = tile * 16;
#pragma unroll
  for (int ks = 0; ks < 2; ++ks) {
    short8 af = *reinterpret_cast<const short8*>(&x[(size_t)(r0 + m) * K + ks * 32 + q * 8]);
#pragma unroll
    for (int ct = 0; ct < 4; ++ct)
      acc[ct] = __builtin_amdgcn_mfma_f32_16x16x32_bf16(af, bfr[ct][ks], acc[ct], 0, 0, 0);
  }
  float dv[4];
#pragma unroll
  for (int r = 0; r < 4; ++r) dv[r] = dinv[r0 + q * 4 + r];
#pragma unroll
  for (int ct = 0; ct < 4; ++ct)
#pragma unroll
    for (int r = 0; r < 4; ++r) {
      int row = r0 + q * 4 + r, col = ct * 16 + m;
      hs[row * 64 + col] = f2bf(acc[ct][r] * dv[r]);
    }
}

// ---------- fused aggregate + bias + LayerNorm + GELU (+ optional head) ----------
// hs is dinv-prescaled:  out_pre_b = dinv[n] * (hs[n] + sum_{src->n} hs[src])
template <int FINAL>
__global__ __launch_bounds__(256) void k_agg(const short* __restrict__ hs,
                                             const float* __restrict__ dinv,
                                             const int* __restrict__ rowptr,
                                             const int* __restrict__ csr,
                                             const float* __restrict__ bias,
                                             const float* __restrict__ gam,
                                             const float* __restrict__ bet,
                                             const float* __restrict__ Wh,
                                             const float* __restrict__ bh,
                                             void* __restrict__ out) {
  int wid = threadIdx.x >> 6, lane = threadIdx.x & 63;
  int n = blockIdx.x * 4 + wid;
  if (n >= NODES) return;
  int e0 = rowptr[n], e1 = rowptr[n + 1];
  float dn = dinv[n];
  float acc0 = bf2f(hs[(size_t)n * 64 + lane]);  // self term (pre-scaled)
  float acc1 = 0.f;
  // 8 edges per batch: 8 lanes load indices, broadcast, 8 gathers in flight.
  for (int base = e0; base < e1; base += 8) {
    int cnt = e1 - base;
    if (cnt > 8) cnt = 8;
    int a = base + (lane < cnt ? lane : 0);  // clamp: always a valid in-row index
    int sidx = csr[a];
    int s[8];
#pragma unroll
    for (int j = 0; j < 8; ++j) s[j] = __shfl(sidx, j, 64);
    float v[8];
#pragma unroll
    for (int j = 0; j < 8; ++j) v[j] = bf2f(hs[(size_t)s[j] * 64 + lane]);  // tail j>=cnt: dup of j=0 line, L1 hit
#pragma unroll
    for (int j = 0; j < 8; ++j) {
      float add = (j < cnt) ? v[j] : 0.f;
      if (j & 1) acc1 += add; else acc0 += add;
    }
  }
  float acc = (acc0 + acc1) * dn + bias[lane];
  float mu = wave_sum(acc) * (1.0f / 64.0f);
  float d = acc - mu;
  float var = wave_sum(d * d) * (1.0f / 64.0f);
  float v = d * rsqrtf(var + 1e-5f) * gam[lane] + bet[lane];
  float u = 0.5f * v * (1.0f + erff(v * 0.70710678118654752f));  // exact GELU
  if (FINAL) {
    float p = wave_sum(u * Wh[lane]);
    if (lane == 0) ((float*)out)[n] = p + bh[0];
  } else {
    ((short*)out)[n * 64 + lane] = f2bf(u);
  }
}

extern "C" void kernel_launch(void* const* d_in, const int* in_sizes, int n_in,
                              void* d_out, int out_size, void* d_ws, size_t ws_size,
                              hipStream_t stream) {
  const float* x  = (const float*)d_in[0];
  const int* ei   = (const int*)d_in[1];
  const float* W1 = (const float*)d_in[2];
  const float* b1 = (const float*)d_in[3];
  const float* g1 = (const float*)d_in[4];
  const float* be1= (const float*)d_in[5];
  const float* W2 = (const float*)d_in[6];
  const float* b2 = (const float*)d_in[7];
  const float* g2 = (const float*)d_in[8];
  const float* be2= (const float*)d_in[9];
  const float* W3 = (const float*)d_in[10];
  const float* b3 = (const float*)d_in[11];
  const float* g3 = (const float*)d_in[12];
  const float* be3= (const float*)d_in[13];
  const float* Wh = (const float*)d_in[14];
  const float* bh = (const float*)d_in[15];
  const int* srcp = ei;
  const int* dstp = ei + EDGES;

  char* ws = (char*)d_ws;
  size_t off = 0;
  auto take = [&](size_t bytes) {
    char* p = ws + off;
    off = (off + bytes + 255) & ~(size_t)255;
    return p;
  };
  int* deg    = (int*)take((size_t)NODES * 4);
  float* dinv = (float*)take((size_t)NODES * 4);
  int* rowptr = (int*)take((size_t)(NODES + 1) * 4);
  int* cursor = (int*)take((size_t)NODES * 4);
  int* part   = (int*)take(512);
  int* csr    = (int*)take((size_t)EDGES * 4);
  short* hs   = (short*)take((size_t)NODES * 64 * 2);
  short* xb   = (short*)take((size_t)NODES * 64 * 2);

  (void)hipMemsetAsync(deg, 0, (size_t)NODES * 4, stream);
  int nb = (NODES + SCAN_CHUNK - 1) / SCAN_CHUNK;  // 98
  k_count<<<(EDGES + 255) / 256, 256, 0, stream>>>(dstp, deg);
  k_dinv<<<(NODES + 255) / 256, 256, 0, stream>>>(deg, dinv);
  k_scan1<<<nb, 256, 0, stream>>>(deg, part);
  k_scan2<<<1, 128, 0, stream>>>(part, nb);
  k_scan3<<<nb, 256, 0, stream>>>(deg, part, rowptr, cursor);
  k_fill<<<(EDGES + 255) / 256, 256, 0, stream>>>(srcp, dstp, cursor, csr);

  int gemm_grid = (NODES / 16 + 3) / 4;  // 1563 blocks x 4 waves
  k_gemm_f32<128><<<gemm_grid, 256, 0, stream>>>(x, W1, dinv, hs);
  k_agg<0><<<NODES / 4, 256, 0, stream>>>(hs, dinv, rowptr, csr, b1, g1, be1, nullptr, nullptr, xb);
  k_gemm_bf<<<gemm_grid, 256, 0, stream>>>(xb, W2, dinv, hs);
  k_agg<0><<<NODES / 4, 256, 0, stream>>>(hs, dinv, rowptr, csr, b2, g2, be2, nullptr, nullptr, xb);
  k_gemm_bf<<<gemm_grid, 256, 0, stream>>>(xb, W3, dinv, hs);
  k_agg<1><<<NODES / 4, 256, 0, stream>>>(hs, dinv, rowptr, csr, b3, g3, be3, Wh, bh, d_out);
}

// Round 8
// 488.876 us; speedup vs baseline: 1.6217x; 1.0225x over previous
//
#include <hip/hip_runtime.h>
#include <math.h>

#define NODES 100000
#define EDGES 1600000
#define INDIM 128
#define HDIM 64
#define SCAN_CHUNK 1024
#define NB 391        // ceil(NODES/256) dst-range buckets (256 nodes each)
#define BCAP 768      // capacity per sub-bucket (mean 512, >10 sigma slack)
#define SUBB (NB * 8) // 8 XCD-local sub-buckets per bucket

typedef __attribute__((ext_vector_type(8))) short short8;
typedef __attribute__((ext_vector_type(4))) float floatx4;

__device__ __forceinline__ float wave_sum(float x) {
#pragma unroll
  for (int o = 32; o > 0; o >>= 1) x += __shfl_xor(x, o, 64);
  return x;
}

// bf16 <-> fp32 without relying on __hip_bfloat16 struct internals (RNE).
__device__ __forceinline__ short f2bf(float f) {
  union { float f; unsigned u; } v;
  v.f = f;
  unsigned r = 0x7fffu + ((v.u >> 16) & 1u);
  return (short)((v.u + r) >> 16);
}
__device__ __forceinline__ float bf2f(short s) {
  union { unsigned u; float f; } v;
  v.u = ((unsigned)(unsigned short)s) << 16;
  return v.f;
}

// ---------- phase A: bin edges into dst-range x XCD sub-buckets ----------
// record = src (17b) | (dst & 255) << 17
__global__ void k_bin(const int* __restrict__ src, const int* __restrict__ dst,
                      int* __restrict__ bins, int* __restrict__ bcur) {
  int e = blockIdx.x * blockDim.x + threadIdx.x;
  if (e >= EDGES) return;
  int d = dst[e], s = src[e];
  int sub = (d >> 8) * 8 + (blockIdx.x & 7);  // blockIdx%8 ~ XCD (perf heuristic only)
  int pos = atomicAdd(&bcur[sub], 1);
  if (pos < BCAP) bins[sub * BCAP + pos] = s | ((d & 255) << 17);
}

// ---------- phase A2: per-bucket LDS histogram -> deg + dinv (no global atomics) ----------
__global__ __launch_bounds__(256) void k_hist(const int* __restrict__ bins,
                                              const int* __restrict__ bcur,
                                              int* __restrict__ deg,
                                              float* __restrict__ dinv) {
  __shared__ int cnt[256];
  int b = blockIdx.x;
  cnt[threadIdx.x] = 0;
  __syncthreads();
  for (int x = 0; x < 8; ++x) {
    int sub = b * 8 + x;
    int c = bcur[sub]; if (c > BCAP) c = BCAP;
    for (int i = threadIdx.x; i < c; i += 256)
      atomicAdd(&cnt[(bins[sub * BCAP + i] >> 17) & 255], 1);
  }
  __syncthreads();
  int n = b * 256 + threadIdx.x;
  if (n < NODES) {
    int c = cnt[threadIdx.x];
    deg[n] = c;
    dinv[n] = rsqrtf((float)c + 1.0f);
  }
}

// ---------- scan (3-phase exclusive prefix over deg) ----------
__global__ void k_scan1(const int* __restrict__ deg, int* __restrict__ part) {
  __shared__ int sw[4];
  int b = blockIdx.x, t = threadIdx.x;
  int base = b * SCAN_CHUNK;
  int s = 0;
#pragma unroll
  for (int j = 0; j < 4; ++j) {
    int i = base + t * 4 + j;
    if (i < NODES) s += deg[i];
  }
  for (int o = 32; o > 0; o >>= 1) s += __shfl_xor(s, o, 64);
  if ((t & 63) == 0) sw[t >> 6] = s;
  __syncthreads();
  if (t == 0) part[b] = sw[0] + sw[1] + sw[2] + sw[3];
}

__global__ void k_scan2(int* part, int nb) {
  __shared__ int sm[128];
  int t = threadIdx.x;
  int v = (t < nb) ? part[t] : 0;
  sm[t] = v;
  __syncthreads();
  for (int o = 1; o < 128; o <<= 1) {
    int u = (t >= o) ? sm[t - o] : 0;
    __syncthreads();
    sm[t] += u;
    __syncthreads();
  }
  if (t < nb) part[t] = sm[t] - v;  // exclusive
}

__global__ void k_scan3(const int* __restrict__ deg, const int* __restrict__ part,
                        int* __restrict__ rowptr) {
  __shared__ int wtot[4];
  int b = blockIdx.x, t = threadIdx.x;
  int lane = t & 63, wid = t >> 6;
  int base = b * SCAN_CHUNK;
  int d[4];
  int s = 0;
#pragma unroll
  for (int j = 0; j < 4; ++j) {
    int i = base + t * 4 + j;
    d[j] = (i < NODES) ? deg[i] : 0;
    s += d[j];
  }
  int inc = s;
#pragma unroll
  for (int o = 1; o < 64; o <<= 1) {
    int u = __shfl_up(inc, o, 64);
    if (lane >= o) inc += u;
  }
  if (lane == 63) wtot[wid] = inc;
  __syncthreads();
  int wpre = 0;
  for (int w = 0; w < wid; ++w) wpre += wtot[w];
  int off = part[b] + wpre + inc - s;
#pragma unroll
  for (int j = 0; j < 4; ++j) {
    int i = base + t * 4 + j;
    if (i < NODES) { rowptr[i] = off; off += d[j]; }
  }
  if (b == 0 && t == 0) rowptr[NODES] = EDGES;
}

// ---------- phase B: fill csr; block owns one bucket; LDS cursors; local stores ----------
__global__ __launch_bounds__(256) void k_fillb(const int* __restrict__ bins,
                                               const int* __restrict__ bcur,
                                               const int* __restrict__ rowptr,
                                               int* __restrict__ csr) {
  __shared__ int cur[256];
  int b = blockIdx.x;
  int n = b * 256 + threadIdx.x;
  cur[threadIdx.x] = (n < NODES) ? rowptr[n] : 0;
  __syncthreads();
  for (int x = 0; x < 8; ++x) {
    int sub = b * 8 + x;
    int c = bcur[sub]; if (c > BCAP) c = BCAP;
    for (int i = threadIdx.x; i < c; i += 256) {
      int pk = bins[sub * BCAP + i];
      int p = atomicAdd(&cur[(pk >> 17) & 255], 1);
      csr[p] = pk & 0x1FFFF;
    }
  }
}

// ---------- GEMM (fp32 acts): [N,K] fp32 @ [K,64] fp32 -> hs = (x@W)*dinv[row], bf16 ----------
template <int K>
__global__ __launch_bounds__(256) void k_gemm_f32(const float* __restrict__ x,
                                                  const float* __restrict__ W,
                                                  const float* __restrict__ dinv,
                                                  short* __restrict__ hs) {
  constexpr int KP = K + 8;
  __shared__ short wt[64 * KP];
  for (int idx = threadIdx.x; idx < K * 64; idx += 256) {
    int k = idx >> 6, n = idx & 63;
    wt[n * KP + k] = f2bf(W[idx]);  // W^T staged as bf16
  }
  __syncthreads();
  int wid = threadIdx.x >> 6, lane = threadIdx.x & 63;
  int tile = blockIdx.x * 4 + wid;
  if (tile * 16 >= NODES) return;
  int m = lane & 15, q = lane >> 4;

  short8 bfr[4][K / 32];
#pragma unroll
  for (int ct = 0; ct < 4; ++ct)
#pragma unroll
    for (int ks = 0; ks < K / 32; ++ks)
      bfr[ct][ks] = *reinterpret_cast<const short8*>(&wt[(ct * 16 + m) * KP + ks * 32 + q * 8]);

  floatx4 acc[4];
#pragma unroll
  for (int ct = 0; ct < 4; ++ct) acc[ct] = {0.f, 0.f, 0.f, 0.f};
  int r0 = tile * 16;
#pragma unroll
  for (int ks = 0; ks < K / 32; ++ks) {
    const float* xp = &x[(size_t)(r0 + m) * K + ks * 32 + q * 8];
    floatx4 a0 = *reinterpret_cast<const floatx4*>(xp);
    floatx4 a1 = *reinterpret_cast<const floatx4*>(xp + 4);
    short8 af;
#pragma unroll
    for (int j = 0; j < 4; ++j) { af[j] = f2bf(a0[j]); af[4 + j] = f2bf(a1[j]); }
#pragma unroll
    for (int ct = 0; ct < 4; ++ct)
      acc[ct] = __builtin_amdgcn_mfma_f32_16x16x32_bf16(af, bfr[ct][ks], acc[ct], 0, 0, 0);
  }
  // C/D: col = lane&15, row = (lane>>4)*4 + reg   [measured m89/m91]
  float dv[4];
#pragma unroll
  for (int r = 0; r < 4; ++r) dv[r] = dinv[r0 + q * 4 + r];
#pragma unroll
  for (int ct = 0; ct < 4; ++ct)
#pragma unroll
    for (int r = 0; r < 4; ++r) {
      int row = r0 + q * 4 + r, col = ct * 16 + m;
      hs[row * 64 + col] = f2bf(acc[ct][r] * dv[r]);
    }
}

// ---------- GEMM (bf16 acts): [N,64] bf16 @ [64,64] fp32 -> hs bf16 (dinv-prescaled) ----------
__global__ __launch_bounds__(256) void k_gemm_bf(const short* __restrict__ x,
                                                 const float* __restrict__ W,
                                                 const float* __restrict__ dinv,
                                                 short* __restrict__ hs) {
  constexpr int K = 64, KP = K + 8;
  __shared__ short wt[64 * KP];
  for (int idx = threadIdx.x; idx < K * 64; idx += 256) {
    int k = idx >> 6, n = idx & 63;
    wt[n * KP + k] = f2bf(W[idx]);
  }
  __syncthreads();
  int wid = threadIdx.x >> 6, lane = threadIdx.x & 63;
  int tile = blockIdx.x * 4 + wid;
  if (tile * 16 >= NODES) return;
  int m = lane & 15, q = lane >> 4;

  short8 bfr[4][2];
#pragma unroll
  for (int ct = 0; ct < 4; ++ct)
#pragma unroll
    for (int ks = 0; ks < 2; ++ks)
      bfr[ct][ks] = *reinterpret_cast<const short8*>(&wt[(ct * 16 + m) * KP + ks * 32 + q * 8]);

  floatx4 acc[4];
#pragma unroll
  for (int ct = 0; ct < 4; ++ct) acc[ct] = {0.f, 0.f, 0.f, 0.f};
  int r0 = tile * 16;
#pragma unroll
  for (int ks = 0; ks < 2; ++ks) {
    short8 af = *reinterpret_cast<const short8*>(&x[(size_t)(r0 + m) * K + ks * 32 + q * 8]);
#pragma unroll
    for (int ct = 0; ct < 4; ++ct)
      acc[ct] = __builtin_amdgcn_mfma_f32_16x16x32_bf16(af, bfr[ct][ks], acc[ct], 0, 0, 0);
  }
  float dv[4];
#pragma unroll
  for (int r = 0; r < 4; ++r) dv[r] = dinv[r0 + q * 4 + r];
#pragma unroll
  for (int ct = 0; ct < 4; ++ct)
#pragma unroll
    for (int r = 0; r < 4; ++r) {
      int row = r0 + q * 4 + r, col = ct * 16 + m;
      hs[row * 64 + col] = f2bf(acc[ct][r] * dv[r]);
    }
}

// ---------- fused aggregate + bias + LayerNorm + GELU (+ optional head) ----------
// hs is dinv-prescaled:  out_pre_b = dinv[n] * (hs[n] + sum_{src->n} hs[src])
template <int FINAL>
__global__ __launch_bounds__(256) void k_agg(const short* __restrict__ hs,
                                             const float* __restrict__ dinv,
                                             const int* __restrict__ rowptr,
                                             const int* __restrict__ csr,
                                             const float* __restrict__ bias,
                                             const float* __restrict__ gam,
                                             const float* __restrict__ bet,
                                             const float* __restrict__ Wh,
                                             const float* __restrict__ bh,
                                             void* __restrict__ out) {
  int wid = threadIdx.x >> 6, lane = threadIdx.x & 63;
  int n = blockIdx.x * 4 + wid;
  if (n >= NODES) return;
  int e0 = rowptr[n], e1 = rowptr[n + 1];
  float dn = dinv[n];
  float acc0 = bf2f(hs[(size_t)n * 64 + lane]);  // self term (pre-scaled)
  float acc1 = 0.f;
  // 8 edges per batch: 8 lanes load indices, broadcast, 8 gathers in flight.
  for (int base = e0; base < e1; base += 8) {
    int cnt = e1 - base;
    if (cnt > 8) cnt = 8;
    int a = base + (lane < cnt ? lane : 0);  // clamp: always a valid in-row index
    int sidx = csr[a];
    int s[8];
#pragma unroll
    for (int j = 0; j < 8; ++j) s[j] = __shfl(sidx, j, 64);
    float v[8];
#pragma unroll
    for (int j = 0; j < 8; ++j) v[j] = bf2f(hs[(size_t)s[j] * 64 + lane]);
#pragma unroll
    for (int j = 0; j < 8; ++j) {
      float add = (j < cnt) ? v[j] : 0.f;
      if (j & 1) acc1 += add; else acc0 += add;
    }
  }
  float acc = (acc0 + acc1) * dn + bias[lane];
  float mu = wave_sum(acc) * (1.0f / 64.0f);
  float d = acc - mu;
  float var = wave_sum(d * d) * (1.0f / 64.0f);
  float v = d * rsqrtf(var + 1e-5f) * gam[lane] + bet[lane];
  float u = 0.5f * v * (1.0f + erff(v * 0.70710678118654752f));  // exact GELU
  if (FINAL) {
    float p = wave_sum(u * Wh[lane]);
    if (lane == 0) ((float*)out)[n] = p + bh[0];
  } else {
    ((short*)out)[n * 64 + lane] = f2bf(u);
  }
}

extern "C" void kernel_launch(void* const* d_in, const int* in_sizes, int n_in,
                              void* d_out, int out_size, void* d_ws, size_t ws_size,
                              hipStream_t stream) {
  const float* x  = (const float*)d_in[0];
  const int* ei   = (const int*)d_in[1];
  const float* W1 = (const float*)d_in[2];
  const float* b1 = (const float*)d_in[3];
  const float* g1 = (const float*)d_in[4];
  const float* be1= (const float*)d_in[5];
  const float* W2 = (const float*)d_in[6];
  const float* b2 = (const float*)d_in[7];
  const float* g2 = (const float*)d_in[8];
  const float* be2= (const float*)d_in[9];
  const float* W3 = (const float*)d_in[10];
  const float* b3 = (const float*)d_in[11];
  const float* g3 = (const float*)d_in[12];
  const float* be3= (const float*)d_in[13];
  const float* Wh = (const float*)d_in[14];
  const float* bh = (const float*)d_in[15];
  const int* srcp = ei;
  const int* dstp = ei + EDGES;

  char* ws = (char*)d_ws;
  size_t off = 0;
  auto take = [&](size_t bytes) {
    char* p = ws + off;
    off = (off + bytes + 255) & ~(size_t)255;
    return p;
  };
  int* deg    = (int*)take((size_t)NODES * 4);
  float* dinv = (float*)take((size_t)NODES * 4);
  int* rowptr = (int*)take((size_t)(NODES + 1) * 4);
  int* part   = (int*)take(512);
  int* csr    = (int*)take((size_t)EDGES * 4);
  short* hs   = (short*)take((size_t)NODES * 64 * 2);   // 12.8 MB
  short* xb   = (short*)take((size_t)NODES * 64 * 2);   // 12.8 MB
  // bins/bcur alias hs/xb: dead before first GEMM writes hs.
  int* bins   = (int*)hs;                                // SUBB*BCAP*4 = 9.6 MB <= 12.8
  int* bcur   = (int*)xb;                                // SUBB*4 = 12.5 KB

  (void)hipMemsetAsync(bcur, 0, (size_t)SUBB * 4, stream);
  k_bin<<<(EDGES + 255) / 256, 256, 0, stream>>>(srcp, dstp, bins, bcur);
  k_hist<<<NB, 256, 0, stream>>>(bins, bcur, deg, dinv);
  int nb = (NODES + SCAN_CHUNK - 1) / SCAN_CHUNK;  // 98
  k_scan1<<<nb, 256, 0, stream>>>(deg, part);
  k_scan2<<<1, 128, 0, stream>>>(part, nb);
  k_scan3<<<nb, 256, 0, stream>>>(deg, part, rowptr);
  k_fillb<<<NB, 256, 0, stream>>>(bins, bcur, rowptr, csr);

  int gemm_grid = (NODES / 16 + 3) / 4;  // 1563 blocks x 4 waves
  k_gemm_f32<128><<<gemm_grid, 256, 0, stream>>>(x, W1, dinv, hs);
  k_agg<0><<<NODES / 4, 256, 0, stream>>>(hs, dinv, rowptr, csr, b1, g1, be1, nullptr, nullptr, xb);
  k_gemm_bf<<<gemm_grid, 256, 0, stream>>>(xb, W2, dinv, hs);
  k_agg<0><<<NODES / 4, 256, 0, stream>>>(hs, dinv, rowptr, csr, b2, g2, be2, nullptr, nullptr, xb);
  k_gemm_bf<<<gemm_grid, 256, 0, stream>>>(xb, W3, dinv, hs);
  k_agg<1><<<NODES / 4, 256, 0, stream>>>(hs, dinv, rowptr, csr, b3, g3, be3, Wh, bh, d_out);
}

// Round 9
// 436.823 us; speedup vs baseline: 1.8149x; 1.1192x over previous
//
#include <hip/hip_runtime.h>
#include <math.h>

#define NODES 100000
#define EDGES 1600000
#define SCAN_CHUNK 1024
#define NB 391        // ceil(NODES/256) dst-range buckets (256 nodes each)
#define BCAP 768      // capacity per sub-bucket (mean 512, >10 sigma slack)
#define SUBB (NB * 8) // 8 XCD sub-buckets per bucket

typedef __attribute__((ext_vector_type(8))) short short8;
typedef __attribute__((ext_vector_type(4))) float floatx4;

__device__ __forceinline__ float half_sum(float x) {  // reduce within 32-lane half-wave
#pragma unroll
  for (int o = 16; o > 0; o >>= 1) x += __shfl_xor(x, o, 64);
  return x;
}

// bf16 <-> fp32 (RNE), no dependence on __hip_bfloat16 internals.
__device__ __forceinline__ short f2bf(float f) {
  union { float f; unsigned u; } v;
  v.f = f;
  unsigned r = 0x7fffu + ((v.u >> 16) & 1u);
  return (short)((v.u + r) >> 16);
}
__device__ __forceinline__ float bf2f(short s) {
  union { unsigned u; float f; } v;
  v.u = ((unsigned)(unsigned short)s) << 16;
  return v.f;
}
__device__ __forceinline__ float bflo(unsigned p) {
  union { unsigned u; float f; } v; v.u = p << 16; return v.f;
}
__device__ __forceinline__ float bfhi(unsigned p) {
  union { unsigned u; float f; } v; v.u = p & 0xffff0000u; return v.f;
}

__device__ __forceinline__ int xcc_id() {  // [measured m09] perf heuristic only
  int x;
  asm volatile("s_getreg_b32 %0, hwreg(HW_REG_XCC_ID)" : "=s"(x));
  return x & 7;
}

// ---------- phase A: bin edges; sub-bucket = (dst-range, real XCD) ----------
// record = src (17b) | (dst & 255) << 17
__global__ void k_bin(const int* __restrict__ src, const int* __restrict__ dst,
                      int* __restrict__ bins, int* __restrict__ bcur) {
  int e = blockIdx.x * blockDim.x + threadIdx.x;
  if (e >= EDGES) return;
  int xc = xcc_id();
  int d = dst[e], s = src[e];
  int sub = (d >> 8) * 8 + xc;  // all appenders of this sub live on XCD xc -> local L2 line merge
  int pos = atomicAdd(&bcur[sub], 1);
  if (pos < BCAP) bins[sub * BCAP + pos] = s | ((d & 255) << 17);
}

// ---------- phase A2: per-bucket LDS histogram -> deg + dinv ----------
__global__ __launch_bounds__(256) void k_hist(const int* __restrict__ bins,
                                              const int* __restrict__ bcur,
                                              int* __restrict__ deg,
                                              float* __restrict__ dinv) {
  __shared__ int cnt[256];
  int b = blockIdx.x;
  cnt[threadIdx.x] = 0;
  __syncthreads();
  for (int x = 0; x < 8; ++x) {
    int sub = b * 8 + x;
    int c = bcur[sub]; if (c > BCAP) c = BCAP;
    for (int i = threadIdx.x; i < c; i += 256)
      atomicAdd(&cnt[(bins[sub * BCAP + i] >> 17) & 255], 1);
  }
  __syncthreads();
  int n = b * 256 + threadIdx.x;
  if (n < NODES) {
    int c = cnt[threadIdx.x];
    deg[n] = c;
    dinv[n] = rsqrtf((float)c + 1.0f);
  }
}

// ---------- scan (3-phase exclusive prefix over deg) ----------
__global__ void k_scan1(const int* __restrict__ deg, int* __restrict__ part) {
  __shared__ int sw[4];
  int b = blockIdx.x, t = threadIdx.x;
  int base = b * SCAN_CHUNK;
  int s = 0;
#pragma unroll
  for (int j = 0; j < 4; ++j) {
    int i = base + t * 4 + j;
    if (i < NODES) s += deg[i];
  }
  for (int o = 32; o > 0; o >>= 1) s += __shfl_xor(s, o, 64);
  if ((t & 63) == 0) sw[t >> 6] = s;
  __syncthreads();
  if (t == 0) part[b] = sw[0] + sw[1] + sw[2] + sw[3];
}

__global__ void k_scan2(int* part, int nb) {
  __shared__ int sm[128];
  int t = threadIdx.x;
  int v = (t < nb) ? part[t] : 0;
  sm[t] = v;
  __syncthreads();
  for (int o = 1; o < 128; o <<= 1) {
    int u = (t >= o) ? sm[t - o] : 0;
    __syncthreads();
    sm[t] += u;
    __syncthreads();
  }
  if (t < nb) part[t] = sm[t] - v;  // exclusive
}

__global__ void k_scan3(const int* __restrict__ deg, const int* __restrict__ part,
                        int* __restrict__ rowptr) {
  __shared__ int wtot[4];
  int b = blockIdx.x, t = threadIdx.x;
  int lane = t & 63, wid = t >> 6;
  int base = b * SCAN_CHUNK;
  int d[4];
  int s = 0;
#pragma unroll
  for (int j = 0; j < 4; ++j) {
    int i = base + t * 4 + j;
    d[j] = (i < NODES) ? deg[i] : 0;
    s += d[j];
  }
  int inc = s;
#pragma unroll
  for (int o = 1; o < 64; o <<= 1) {
    int u = __shfl_up(inc, o, 64);
    if (lane >= o) inc += u;
  }
  if (lane == 63) wtot[wid] = inc;
  __syncthreads();
  int wpre = 0;
  for (int w = 0; w < wid; ++w) wpre += wtot[w];
  int off = part[b] + wpre + inc - s;
#pragma unroll
  for (int j = 0; j < 4; ++j) {
    int i = base + t * 4 + j;
    if (i < NODES) { rowptr[i] = off; off += d[j]; }
  }
  if (b == 0 && t == 0) rowptr[NODES] = EDGES;
}

// ---------- phase B: fill csr; block owns bucket; LDS cursors ----------
__global__ __launch_bounds__(256) void k_fillb(const int* __restrict__ bins,
                                               const int* __restrict__ bcur,
                                               const int* __restrict__ rowptr,
                                               int* __restrict__ csr) {
  __shared__ int cur[256];
  int b = blockIdx.x;
  int n = b * 256 + threadIdx.x;
  cur[threadIdx.x] = (n < NODES) ? rowptr[n] : 0;
  __syncthreads();
  for (int x = 0; x < 8; ++x) {
    int sub = b * 8 + x;
    int c = bcur[sub]; if (c > BCAP) c = BCAP;
    for (int i = threadIdx.x; i < c; i += 256) {
      int pk = bins[sub * BCAP + i];
      int p = atomicAdd(&cur[(pk >> 17) & 255], 1);
      csr[p] = pk & 0x1FFFF;
    }
  }
}

// ---------- GEMM (fp32 acts): [N,K] fp32 @ [K,64] -> hs = (x@W)*dinv[row], bf16 ----------
template <int K>
__global__ __launch_bounds__(256) void k_gemm_f32(const float* __restrict__ x,
                                                  const float* __restrict__ W,
                                                  const float* __restrict__ dinv,
                                                  short* __restrict__ hs) {
  constexpr int KP = K + 8;
  __shared__ short wt[64 * KP];
  for (int idx = threadIdx.x; idx < K * 64; idx += 256) {
    int k = idx >> 6, n = idx & 63;
    wt[n * KP + k] = f2bf(W[idx]);  // W^T staged as bf16
  }
  __syncthreads();
  int wid = threadIdx.x >> 6, lane = threadIdx.x & 63;
  int tile = blockIdx.x * 4 + wid;
  if (tile * 16 >= NODES) return;
  int m = lane & 15, q = lane >> 4;

  short8 bfr[4][K / 32];
#pragma unroll
  for (int ct = 0; ct < 4; ++ct)
#pragma unroll
    for (int ks = 0; ks < K / 32; ++ks)
      bfr[ct][ks] = *reinterpret_cast<const short8*>(&wt[(ct * 16 + m) * KP + ks * 32 + q * 8]);

  floatx4 acc[4];
#pragma unroll
  for (int ct = 0; ct < 4; ++ct) acc[ct] = {0.f, 0.f, 0.f, 0.f};
  int r0 = tile * 16;
#pragma unroll
  for (int ks = 0; ks < K / 32; ++ks) {
    const float* xp = &x[(size_t)(r0 + m) * K + ks * 32 + q * 8];
    floatx4 a0 = *reinterpret_cast<const floatx4*>(xp);
    floatx4 a1 = *reinterpret_cast<const floatx4*>(xp + 4);
    short8 af;
#pragma unroll
    for (int j = 0; j < 4; ++j) { af[j] = f2bf(a0[j]); af[4 + j] = f2bf(a1[j]); }
#pragma unroll
    for (int ct = 0; ct < 4; ++ct)
      acc[ct] = __builtin_amdgcn_mfma_f32_16x16x32_bf16(af, bfr[ct][ks], acc[ct], 0, 0, 0);
  }
  // C/D: col = lane&15, row = (lane>>4)*4 + reg   [measured m89/m91]
  float dv[4];
#pragma unroll
  for (int r = 0; r < 4; ++r) dv[r] = dinv[r0 + q * 4 + r];
#pragma unroll
  for (int ct = 0; ct < 4; ++ct)
#pragma unroll
    for (int r = 0; r < 4; ++r) {
      int row = r0 + q * 4 + r, col = ct * 16 + m;
      hs[row * 64 + col] = f2bf(acc[ct][r] * dv[r]);
    }
}

// ---------- GEMM (bf16 acts): [N,64] bf16 @ [64,64] -> hs bf16 (dinv-prescaled) ----------
__global__ __launch_bounds__(256) void k_gemm_bf(const short* __restrict__ x,
                                                 const float* __restrict__ W,
                                                 const float* __restrict__ dinv,
                                                 short* __restrict__ hs) {
  constexpr int K = 64, KP = K + 8;
  __shared__ short wt[64 * KP];
  for (int idx = threadIdx.x; idx < K * 64; idx += 256) {
    int k = idx >> 6, n = idx & 63;
    wt[n * KP + k] = f2bf(W[idx]);
  }
  __syncthreads();
  int wid = threadIdx.x >> 6, lane = threadIdx.x & 63;
  int tile = blockIdx.x * 4 + wid;
  if (tile * 16 >= NODES) return;
  int m = lane & 15, q = lane >> 4;

  short8 bfr[4][2];
#pragma unroll
  for (int ct = 0; ct < 4; ++ct)
#pragma unroll
    for (int ks = 0; ks < 2; ++ks)
      bfr[ct][ks] = *reinterpret_cast<const short8*>(&wt[(ct * 16 + m) * KP + ks * 32 + q * 8]);

  floatx4 acc[4];
#pragma unroll
  for (int ct = 0; ct < 4; ++ct) acc[ct] = {0.f, 0.f, 0.f, 0.f};
  int r0 = tile * 16;
#pragma unroll
  for (int ks = 0; ks < 2; ++ks) {
    short8 af = *reinterpret_cast<const short8*>(&x[(size_t)(r0 + m) * K + ks * 32 + q * 8]);
#pragma unroll
    for (int ct = 0; ct < 4; ++ct)
      acc[ct] = __builtin_amdgcn_mfma_f32_16x16x32_bf16(af, bfr[ct][ks], acc[ct], 0, 0, 0);
  }
  float dv[4];
#pragma unroll
  for (int r = 0; r < 4; ++r) dv[r] = dinv[r0 + q * 4 + r];
#pragma unroll
  for (int ct = 0; ct < 4; ++ct)
#pragma unroll
    for (int r = 0; r < 4; ++r) {
      int row = r0 + q * 4 + r, col = ct * 16 + m;
      hs[row * 64 + col] = f2bf(acc[ct][r] * dv[r]);
    }
}

// ---------- fused aggregate + bias + LN + GELU (+ head) ----------
// 2 nodes per wave: half-wave (32 lanes) per node, lane holds 2 packed bf16 features.
// hs dinv-prescaled: pre = dinv[n] * (hs[n] + sum hs[src]) + bias
template <int FINAL>
__global__ __launch_bounds__(256) void k_agg(const short* __restrict__ hs,
                                             const float* __restrict__ dinv,
                                             const int* __restrict__ rowptr,
                                             const int* __restrict__ csr,
                                             const float* __restrict__ bias,
                                             const float* __restrict__ gam,
                                             const float* __restrict__ bet,
                                             const float* __restrict__ Wh,
                                             const float* __restrict__ bh,
                                             void* __restrict__ out) {
  const unsigned* hsu = (const unsigned*)hs;
  int wid = threadIdx.x >> 6, lane = threadIdx.x & 63;
  int ll = lane & 31, hb = lane & 32;          // half-lane, half-base
  int n = blockIdx.x * 8 + wid * 2 + (hb >> 5); // 8 nodes per block
  int e0 = rowptr[n], e1 = rowptr[n + 1];
  float dn = dinv[n];
  unsigned sv = hsu[(size_t)n * 32 + ll];       // self term, 2 features
  float a0 = bflo(sv), a1 = bfhi(sv);
  for (int base = e0; base < e1; base += 8) {
    int cnt = e1 - base;
    if (cnt > 8) cnt = 8;
    int a = base + (ll < cnt ? ll : 0);         // clamp to valid in-row index
    int sidx = csr[a];
    int s[8];
#pragma unroll
    for (int j = 0; j < 8; ++j) s[j] = __shfl(sidx, hb + j, 64);
    unsigned v[8];
#pragma unroll
    for (int j = 0; j < 8; ++j) v[j] = hsu[(size_t)s[j] * 32 + ll];  // 16 gathers/wave in flight
#pragma unroll
    for (int j = 0; j < 8; ++j) {
      if (j < cnt) { a0 += bflo(v[j]); a1 += bfhi(v[j]); }
    }
  }
  float2 bi = ((const float2*)bias)[ll];
  a0 = a0 * dn + bi.x;
  a1 = a1 * dn + bi.y;
  float mu = half_sum(a0 + a1) * (1.0f / 64.0f);
  float d0 = a0 - mu, d1 = a1 - mu;
  float var = half_sum(d0 * d0 + d1 * d1) * (1.0f / 64.0f);
  float rs = rsqrtf(var + 1e-5f);
  float2 gm = ((const float2*)gam)[ll];
  float2 bt = ((const float2*)bet)[ll];
  float v0 = d0 * rs * gm.x + bt.x;
  float v1 = d1 * rs * gm.y + bt.y;
  float u0 = 0.5f * v0 * (1.0f + erff(v0 * 0.70710678118654752f));  // exact GELU
  float u1 = 0.5f * v1 * (1.0f + erff(v1 * 0.70710678118654752f));
  if (FINAL) {
    float2 wh = ((const float2*)Wh)[ll];
    float p = half_sum(u0 * wh.x + u1 * wh.y);
    if (ll == 0) ((float*)out)[n] = p + bh[0];
  } else {
    unsigned pk = (unsigned)(unsigned short)f2bf(u0) |
                  ((unsigned)(unsigned short)f2bf(u1) << 16);
    ((unsigned*)out)[(size_t)n * 32 + ll] = pk;
  }
}

extern "C" void kernel_launch(void* const* d_in, const int* in_sizes, int n_in,
                              void* d_out, int out_size, void* d_ws, size_t ws_size,
                              hipStream_t stream) {
  const float* x  = (const float*)d_in[0];
  const int* ei   = (const int*)d_in[1];
  const float* W1 = (const float*)d_in[2];
  const float* b1 = (const float*)d_in[3];
  const float* g1 = (const float*)d_in[4];
  const float* be1= (const float*)d_in[5];
  const float* W2 = (const float*)d_in[6];
  const float* b2 = (const float*)d_in[7];
  const float* g2 = (const float*)d_in[8];
  const float* be2= (const float*)d_in[9];
  const float* W3 = (const float*)d_in[10];
  const float* b3 = (const float*)d_in[11];
  const float* g3 = (const float*)d_in[12];
  const float* be3= (const float*)d_in[13];
  const float* Wh = (const float*)d_in[14];
  const float* bh = (const float*)d_in[15];
  const int* srcp = ei;
  const int* dstp = ei + EDGES;

  char* ws = (char*)d_ws;
  size_t off = 0;
  auto take = [&](size_t bytes) {
    char* p = ws + off;
    off = (off + bytes + 255) & ~(size_t)255;
    return p;
  };
  int* deg    = (int*)take((size_t)NODES * 4);
  float* dinv = (float*)take((size_t)NODES * 4);
  int* rowptr = (int*)take((size_t)(NODES + 1) * 4);
  int* part   = (int*)take(512);
  int* csr    = (int*)take((size_t)EDGES * 4);
  short* hs   = (short*)take((size_t)NODES * 64 * 2);   // 12.8 MB
  short* xb   = (short*)take((size_t)NODES * 64 * 2);   // 12.8 MB
  // bins/bcur alias hs/xb: dead before first GEMM writes hs.
  int* bins   = (int*)hs;                                // SUBB*BCAP*4 = 9.6 MB
  int* bcur   = (int*)xb;                                // SUBB*4 = 12.5 KB

  (void)hipMemsetAsync(bcur, 0, (size_t)SUBB * 4, stream);
  k_bin<<<(EDGES + 255) / 256, 256, 0, stream>>>(srcp, dstp, bins, bcur);
  k_hist<<<NB, 256, 0, stream>>>(bins, bcur, deg, dinv);
  int nb = (NODES + SCAN_CHUNK - 1) / SCAN_CHUNK;  // 98
  k_scan1<<<nb, 256, 0, stream>>>(deg, part);
  k_scan2<<<1, 128, 0, stream>>>(part, nb);
  k_scan3<<<nb, 256, 0, stream>>>(deg, part, rowptr);
  k_fillb<<<NB, 256, 0, stream>>>(bins, bcur, rowptr, csr);

  int gemm_grid = (NODES / 16 + 3) / 4;  // 1563 blocks x 4 waves
  k_gemm_f32<128><<<gemm_grid, 256, 0, stream>>>(x, W1, dinv, hs);
  k_agg<0><<<NODES / 8, 256, 0, stream>>>(hs, dinv, rowptr, csr, b1, g1, be1, nullptr, nullptr, xb);
  k_gemm_bf<<<gemm_grid, 256, 0, stream>>>(xb, W2, dinv, hs);
  k_agg<0><<<NODES / 8, 256, 0, stream>>>(hs, dinv, rowptr, csr, b2, g2, be2, nullptr, nullptr, xb);
  k_gemm_bf<<<gemm_grid, 256, 0, stream>>>(xb, W3, dinv, hs);
  k_agg<1><<<NODES / 8, 256, 0, stream>>>(hs, dinv, rowptr, csr, b3, g3, be3, Wh, bh, d_out);
}

// Round 10
// 316.926 us; speedup vs baseline: 2.5015x; 1.3783x over previous
//
#include <hip/hip_runtime.h>
#include <math.h>

#define NODES 100000
#define EDGES 1600000
#define SCAN_CHUNK 1024
#define NBUCK 196     // ceil(NODES/512) dst-range buckets (512 nodes each)
#define BCAP2 12288   // capacity per bucket (mean 8163, huge slack)
#define EPB 4096      // edges per binning block

typedef __attribute__((ext_vector_type(8))) short short8;
typedef __attribute__((ext_vector_type(4))) float floatx4;

__device__ __forceinline__ float half_sum(float x) {  // reduce within 32-lane half-wave
#pragma unroll
  for (int o = 16; o > 0; o >>= 1) x += __shfl_xor(x, o, 64);
  return x;
}

// bf16 <-> fp32 (RNE), no dependence on __hip_bfloat16 internals.
__device__ __forceinline__ short f2bf(float f) {
  union { float f; unsigned u; } v;
  v.f = f;
  unsigned r = 0x7fffu + ((v.u >> 16) & 1u);
  return (short)((v.u + r) >> 16);
}
__device__ __forceinline__ float bf2f(short s) {
  union { unsigned u; float f; } v;
  v.u = ((unsigned)(unsigned short)s) << 16;
  return v.f;
}
__device__ __forceinline__ float bflo(unsigned p) {
  union { unsigned u; float f; } v; v.u = p << 16; return v.f;
}
__device__ __forceinline__ float bfhi(unsigned p) {
  union { unsigned u; float f; } v; v.u = p & 0xffff0000u; return v.f;
}

// ---------- phase A: two-pass LDS binning; ~196 global atomics per block ----------
// record = src (17b) | (dst & 511) << 17
__global__ __launch_bounds__(256) void k_bin2(const int* __restrict__ src,
                                              const int* __restrict__ dst,
                                              int* __restrict__ bins,
                                              int* __restrict__ gcur) {
  __shared__ int cnt[NBUCK], gbase[NBUCK], lcur[NBUCK];
  int t = threadIdx.x;
  for (int i = t; i < NBUCK; i += 256) cnt[i] = 0;
  __syncthreads();
  int base = blockIdx.x * EPB;
  int s[16], d[16];
#pragma unroll
  for (int j = 0; j < 16; ++j) {
    int e = base + j * 256 + t;  // coalesced
    if (e < EDGES) {
      s[j] = src[e];
      d[j] = dst[e];
      atomicAdd(&cnt[d[j] >> 9], 1);
    } else {
      d[j] = -1;
    }
  }
  __syncthreads();
  for (int i = t; i < NBUCK; i += 256) {
    int c = cnt[i];
    gbase[i] = c ? atomicAdd(&gcur[i], c) : 0;  // ONE global atomic per (block,bucket)
    lcur[i] = 0;
  }
  __syncthreads();
#pragma unroll
  for (int j = 0; j < 16; ++j) {
    if (d[j] >= 0) {
      int bk = d[j] >> 9;
      int lp = atomicAdd(&lcur[bk], 1);  // LDS atomic (cheap)
      int pos = gbase[bk] + lp;
      if (pos < BCAP2) bins[bk * BCAP2 + pos] = s[j] | ((d[j] & 511) << 17);
    }
  }
}

// ---------- phase A2: per-bucket LDS histogram -> deg + dinv ----------
__global__ __launch_bounds__(256) void k_hist(const int* __restrict__ bins,
                                              const int* __restrict__ gcur,
                                              int* __restrict__ deg,
                                              float* __restrict__ dinv) {
  __shared__ int cnt[512];
  int b = blockIdx.x, t = threadIdx.x;
  cnt[t] = 0; cnt[t + 256] = 0;
  __syncthreads();
  int c = gcur[b]; if (c > BCAP2) c = BCAP2;
  const int* bp = &bins[b * BCAP2];
  for (int i = t; i < c; i += 256)
    atomicAdd(&cnt[(bp[i] >> 17) & 511], 1);
  __syncthreads();
#pragma unroll
  for (int k = 0; k < 2; ++k) {
    int n = b * 512 + t + k * 256;
    if (n < NODES) {
      int cc = cnt[t + k * 256];
      deg[n] = cc;
      dinv[n] = rsqrtf((float)cc + 1.0f);
    }
  }
}

// ---------- scan (3-phase exclusive prefix over deg) ----------
__global__ void k_scan1(const int* __restrict__ deg, int* __restrict__ part) {
  __shared__ int sw[4];
  int b = blockIdx.x, t = threadIdx.x;
  int base = b * SCAN_CHUNK;
  int s = 0;
#pragma unroll
  for (int j = 0; j < 4; ++j) {
    int i = base + t * 4 + j;
    if (i < NODES) s += deg[i];
  }
  for (int o = 32; o > 0; o >>= 1) s += __shfl_xor(s, o, 64);
  if ((t & 63) == 0) sw[t >> 6] = s;
  __syncthreads();
  if (t == 0) part[b] = sw[0] + sw[1] + sw[2] + sw[3];
}

__global__ void k_scan2(int* part, int nb) {
  __shared__ int sm[128];
  int t = threadIdx.x;
  int v = (t < nb) ? part[t] : 0;
  sm[t] = v;
  __syncthreads();
  for (int o = 1; o < 128; o <<= 1) {
    int u = (t >= o) ? sm[t - o] : 0;
    __syncthreads();
    sm[t] += u;
    __syncthreads();
  }
  if (t < nb) part[t] = sm[t] - v;  // exclusive
}

__global__ void k_scan3(const int* __restrict__ deg, const int* __restrict__ part,
                        int* __restrict__ rowptr) {
  __shared__ int wtot[4];
  int b = blockIdx.x, t = threadIdx.x;
  int lane = t & 63, wid = t >> 6;
  int base = b * SCAN_CHUNK;
  int d[4];
  int s = 0;
#pragma unroll
  for (int j = 0; j < 4; ++j) {
    int i = base + t * 4 + j;
    d[j] = (i < NODES) ? deg[i] : 0;
    s += d[j];
  }
  int inc = s;
#pragma unroll
  for (int o = 1; o < 64; o <<= 1) {
    int u = __shfl_up(inc, o, 64);
    if (lane >= o) inc += u;
  }
  if (lane == 63) wtot[wid] = inc;
  __syncthreads();
  int wpre = 0;
  for (int w = 0; w < wid; ++w) wpre += wtot[w];
  int off = part[b] + wpre + inc - s;
#pragma unroll
  for (int j = 0; j < 4; ++j) {
    int i = base + t * 4 + j;
    if (i < NODES) { rowptr[i] = off; off += d[j]; }
  }
  if (b == 0 && t == 0) rowptr[NODES] = EDGES;
}

// ---------- phase B: fill csr; block owns one 512-node bucket; LDS cursors ----------
__global__ __launch_bounds__(256) void k_fillb(const int* __restrict__ bins,
                                               const int* __restrict__ gcur,
                                               const int* __restrict__ rowptr,
                                               int* __restrict__ csr) {
  __shared__ int cur[512];
  int b = blockIdx.x, t = threadIdx.x;
#pragma unroll
  for (int k = 0; k < 2; ++k) {
    int n = b * 512 + t + k * 256;
    cur[t + k * 256] = (n < NODES) ? rowptr[n] : 0;
  }
  __syncthreads();
  int c = gcur[b]; if (c > BCAP2) c = BCAP2;
  const int* bp = &bins[b * BCAP2];
  for (int i = t; i < c; i += 256) {
    int pk = bp[i];
    int p = atomicAdd(&cur[(pk >> 17) & 511], 1);
    csr[p] = pk & 0x1FFFF;
  }
}

// ---------- GEMM (fp32 acts): [N,K] fp32 @ [K,64] -> hs = (x@W)*dinv[row], bf16 ----------
template <int K>
__global__ __launch_bounds__(256) void k_gemm_f32(const float* __restrict__ x,
                                                  const float* __restrict__ W,
                                                  const float* __restrict__ dinv,
                                                  short* __restrict__ hs) {
  constexpr int KP = K + 8;
  __shared__ short wt[64 * KP];
  for (int idx = threadIdx.x; idx < K * 64; idx += 256) {
    int k = idx >> 6, n = idx & 63;
    wt[n * KP + k] = f2bf(W[idx]);  // W^T staged as bf16
  }
  __syncthreads();
  int wid = threadIdx.x >> 6, lane = threadIdx.x & 63;
  int tile = blockIdx.x * 4 + wid;
  if (tile * 16 >= NODES) return;
  int m = lane & 15, q = lane >> 4;

  short8 bfr[4][K / 32];
#pragma unroll
  for (int ct = 0; ct < 4; ++ct)
#pragma unroll
    for (int ks = 0; ks < K / 32; ++ks)
      bfr[ct][ks] = *reinterpret_cast<const short8*>(&wt[(ct * 16 + m) * KP + ks * 32 + q * 8]);

  floatx4 acc[4];
#pragma unroll
  for (int ct = 0; ct < 4; ++ct) acc[ct] = {0.f, 0.f, 0.f, 0.f};
  int r0 = tile * 16;
#pragma unroll
  for (int ks = 0; ks < K / 32; ++ks) {
    const float* xp = &x[(size_t)(r0 + m) * K + ks * 32 + q * 8];
    floatx4 a0 = *reinterpret_cast<const floatx4*>(xp);
    floatx4 a1 = *reinterpret_cast<const floatx4*>(xp + 4);
    short8 af;
#pragma unroll
    for (int j = 0; j < 4; ++j) { af[j] = f2bf(a0[j]); af[4 + j] = f2bf(a1[j]); }
#pragma unroll
    for (int ct = 0; ct < 4; ++ct)
      acc[ct] = __builtin_amdgcn_mfma_f32_16x16x32_bf16(af, bfr[ct][ks], acc[ct], 0, 0, 0);
  }
  // C/D: col = lane&15, row = (lane>>4)*4 + reg   [measured m89/m91]
  float dv[4];
#pragma unroll
  for (int r = 0; r < 4; ++r) dv[r] = dinv[r0 + q * 4 + r];
#pragma unroll
  for (int ct = 0; ct < 4; ++ct)
#pragma unroll
    for (int r = 0; r < 4; ++r) {
      int row = r0 + q * 4 + r, col = ct * 16 + m;
      hs[row * 64 + col] = f2bf(acc[ct][r] * dv[r]);
    }
}

// ---------- GEMM (bf16 acts): [N,64] bf16 @ [64,64] -> hs bf16 (dinv-prescaled) ----------
__global__ __launch_bounds__(256) void k_gemm_bf(const short* __restrict__ x,
                                                 const float* __restrict__ W,
                                                 const float* __restrict__ dinv,
                                                 short* __restrict__ hs) {
  constexpr int K = 64, KP = K + 8;
  __shared__ short wt[64 * KP];
  for (int idx = threadIdx.x; idx < K * 64; idx += 256) {
    int k = idx >> 6, n = idx & 63;
    wt[n * KP + k] = f2bf(W[idx]);
  }
  __syncthreads();
  int wid = threadIdx.x >> 6, lane = threadIdx.x & 63;
  int tile = blockIdx.x * 4 + wid;
  if (tile * 16 >= NODES) return;
  int m = lane & 15, q = lane >> 4;

  short8 bfr[4][2];
#pragma unroll
  for (int ct = 0; ct < 4; ++ct)
#pragma unroll
    for (int ks = 0; ks < 2; ++ks)
      bfr[ct][ks] = *reinterpret_cast<const short8*>(&wt[(ct * 16 + m) * KP + ks * 32 + q * 8]);

  floatx4 acc[4];
#pragma unroll
  for (int ct = 0; ct < 4; ++ct) acc[ct] = {0.f, 0.f, 0.f, 0.f};
  int r0 = tile * 16;
#pragma unroll
  for (int ks = 0; ks < 2; ++ks) {
    short8 af = *reinterpret_cast<const short8*>(&x[(size_t)(r0 + m) * K + ks * 32 + q * 8]);
#pragma unroll
    for (int ct = 0; ct < 4; ++ct)
      acc[ct] = __builtin_amdgcn_mfma_f32_16x16x32_bf16(af, bfr[ct][ks], acc[ct], 0, 0, 0);
  }
  float dv[4];
#pragma unroll
  for (int r = 0; r < 4; ++r) dv[r] = dinv[r0 + q * 4 + r];
#pragma unroll
  for (int ct = 0; ct < 4; ++ct)
#pragma unroll
    for (int r = 0; r < 4; ++r) {
      int row = r0 + q * 4 + r, col = ct * 16 + m;
      hs[row * 64 + col] = f2bf(acc[ct][r] * dv[r]);
    }
}

// ---------- fused aggregate + bias + LN + GELU (+ head) ----------
// 2 nodes per wave: half-wave (32 lanes) per node, lane holds 2 packed bf16 features.
// hs dinv-prescaled: pre = dinv[n] * (hs[n] + sum hs[src]) + bias
template <int FINAL>
__global__ __launch_bounds__(256) void k_agg(const short* __restrict__ hs,
                                             const float* __restrict__ dinv,
                                             const int* __restrict__ rowptr,
                                             const int* __restrict__ csr,
                                             const float* __restrict__ bias,
                                             const float* __restrict__ gam,
                                             const float* __restrict__ bet,
                                             const float* __restrict__ Wh,
                                             const float* __restrict__ bh,
                                             void* __restrict__ out) {
  const unsigned* hsu = (const unsigned*)hs;
  int wid = threadIdx.x >> 6, lane = threadIdx.x & 63;
  int ll = lane & 31, hb = lane & 32;          // half-lane, half-base
  int n = blockIdx.x * 8 + wid * 2 + (hb >> 5); // 8 nodes per block
  int e0 = rowptr[n], e1 = rowptr[n + 1];
  float dn = dinv[n];
  unsigned sv = hsu[(size_t)n * 32 + ll];       // self term, 2 features
  float a0 = bflo(sv), a1 = bfhi(sv);
  for (int base = e0; base < e1; base += 8) {
    int cnt = e1 - base;
    if (cnt > 8) cnt = 8;
    int a = base + (ll < cnt ? ll : 0);         // clamp to valid in-row index
    int sidx = csr[a];
    int s[8];
#pragma unroll
    for (int j = 0; j < 8; ++j) s[j] = __shfl(sidx, hb + j, 64);
    unsigned v[8];
#pragma unroll
    for (int j = 0; j < 8; ++j) v[j] = hsu[(size_t)s[j] * 32 + ll];  // 16 gathers/wave in flight
#pragma unroll
    for (int j = 0; j < 8; ++j) {
      if (j < cnt) { a0 += bflo(v[j]); a1 += bfhi(v[j]); }
    }
  }
  float2 bi = ((const float2*)bias)[ll];
  a0 = a0 * dn + bi.x;
  a1 = a1 * dn + bi.y;
  float mu = half_sum(a0 + a1) * (1.0f / 64.0f);
  float d0 = a0 - mu, d1 = a1 - mu;
  float var = half_sum(d0 * d0 + d1 * d1) * (1.0f / 64.0f);
  float rs = rsqrtf(var + 1e-5f);
  float2 gm = ((const float2*)gam)[ll];
  float2 bt = ((const float2*)bet)[ll];
  float v0 = d0 * rs * gm.x + bt.x;
  float v1 = d1 * rs * gm.y + bt.y;
  float u0 = 0.5f * v0 * (1.0f + erff(v0 * 0.70710678118654752f));  // exact GELU
  float u1 = 0.5f * v1 * (1.0f + erff(v1 * 0.70710678118654752f));
  if (FINAL) {
    float2 wh = ((const float2*)Wh)[ll];
    float p = half_sum(u0 * wh.x + u1 * wh.y);
    if (ll == 0) ((float*)out)[n] = p + bh[0];
  } else {
    unsigned pk = (unsigned)(unsigned short)f2bf(u0) |
                  ((unsigned)(unsigned short)f2bf(u1) << 16);
    ((unsigned*)out)[(size_t)n * 32 + ll] = pk;
  }
}

extern "C" void kernel_launch(void* const* d_in, const int* in_sizes, int n_in,
                              void* d_out, int out_size, void* d_ws, size_t ws_size,
                              hipStream_t stream) {
  const float* x  = (const float*)d_in[0];
  const int* ei   = (const int*)d_in[1];
  const float* W1 = (const float*)d_in[2];
  const float* b1 = (const float*)d_in[3];
  const float* g1 = (const float*)d_in[4];
  const float* be1= (const float*)d_in[5];
  const float* W2 = (const float*)d_in[6];
  const float* b2 = (const float*)d_in[7];
  const float* g2 = (const float*)d_in[8];
  const float* be2= (const float*)d_in[9];
  const float* W3 = (const float*)d_in[10];
  const float* b3 = (const float*)d_in[11];
  const float* g3 = (const float*)d_in[12];
  const float* be3= (const float*)d_in[13];
  const float* Wh = (const float*)d_in[14];
  const float* bh = (const float*)d_in[15];
  const int* srcp = ei;
  const int* dstp = ei + EDGES;

  char* ws = (char*)d_ws;
  size_t off = 0;
  auto take = [&](size_t bytes) {
    char* p = ws + off;
    off = (off + bytes + 255) & ~(size_t)255;
    return p;
  };
  int* deg    = (int*)take((size_t)NODES * 4);
  float* dinv = (float*)take((size_t)NODES * 4);
  int* rowptr = (int*)take((size_t)(NODES + 1) * 4);
  int* part   = (int*)take(512);
  int* csr    = (int*)take((size_t)EDGES * 4);
  short* hs   = (short*)take((size_t)NODES * 64 * 2);   // 12.8 MB
  short* xb   = (short*)take((size_t)NODES * 64 * 2);   // 12.8 MB
  // bins/gcur alias hs/xb: dead before first GEMM writes hs.
  int* bins   = (int*)hs;                                // NBUCK*BCAP2*4 = 9.63 MB
  int* gcur   = (int*)xb;                                // NBUCK*4 = 784 B

  (void)hipMemsetAsync(gcur, 0, (size_t)NBUCK * 4, stream);
  k_bin2<<<(EDGES + EPB - 1) / EPB, 256, 0, stream>>>(srcp, dstp, bins, gcur);
  k_hist<<<NBUCK, 256, 0, stream>>>(bins, gcur, deg, dinv);
  int nb = (NODES + SCAN_CHUNK - 1) / SCAN_CHUNK;  // 98
  k_scan1<<<nb, 256, 0, stream>>>(deg, part);
  k_scan2<<<1, 128, 0, stream>>>(part, nb);
  k_scan3<<<nb, 256, 0, stream>>>(deg, part, rowptr);
  k_fillb<<<NBUCK, 256, 0, stream>>>(bins, gcur, rowptr, csr);

  int gemm_grid = (NODES / 16 + 3) / 4;  // 1563 blocks x 4 waves
  k_gemm_f32<128><<<gemm_grid, 256, 0, stream>>>(x, W1, dinv, hs);
  k_agg<0><<<NODES / 8, 256, 0, stream>>>(hs, dinv, rowptr, csr, b1, g1, be1, nullptr, nullptr, xb);
  k_gemm_bf<<<gemm_grid, 256, 0, stream>>>(xb, W2, dinv, hs);
  k_agg<0><<<NODES / 8, 256, 0, stream>>>(hs, dinv, rowptr, csr, b2, g2, be2, nullptr, nullptr, xb);
  k_gemm_bf<<<gemm_grid, 256, 0, stream>>>(xb, W3, dinv, hs);
  k_agg<1><<<NODES / 8, 256, 0, stream>>>(hs, dinv, rowptr, csr, b3, g3, be3, Wh, bh, d_out);
}

// Round 11
// 298.568 us; speedup vs baseline: 2.6553x; 1.0615x over previous
//
#include <hip/hip_runtime.h>
#include <math.h>

#define NODES 100000
#define EDGES 1600000
#define SCAN_CHUNK 1024
#define NBUCK 196     // ceil(NODES/512) dst-range buckets (512 nodes each)
#define BCAP2 12288   // capacity per bucket (mean 8163, huge slack)
#define EPB 4096      // edges per binning block

typedef __attribute__((ext_vector_type(8))) short short8;
typedef __attribute__((ext_vector_type(4))) float floatx4;
typedef __attribute__((ext_vector_type(4))) unsigned uv4;

// group-of-8 reduction (xor 4,2,1 stays inside an aligned 8-lane group)
__device__ __forceinline__ float gsum8(float x) {
#pragma unroll
  for (int o = 4; o > 0; o >>= 1) x += __shfl_xor(x, o, 64);
  return x;
}

// bf16 <-> fp32 (RNE), no dependence on __hip_bfloat16 internals.
__device__ __forceinline__ short f2bf(float f) {
  union { float f; unsigned u; } v;
  v.f = f;
  unsigned r = 0x7fffu + ((v.u >> 16) & 1u);
  return (short)((v.u + r) >> 16);
}
__device__ __forceinline__ float bflo(unsigned p) {
  union { unsigned u; float f; } v; v.u = p << 16; return v.f;
}
__device__ __forceinline__ float bfhi(unsigned p) {
  union { unsigned u; float f; } v; v.u = p & 0xffff0000u; return v.f;
}

// ---------- phase A: two-pass LDS binning; ~196 global atomics per block ----------
// record = src (17b) | (dst & 511) << 17
__global__ __launch_bounds__(256) void k_bin2(const int* __restrict__ src,
                                              const int* __restrict__ dst,
                                              int* __restrict__ bins,
                                              int* __restrict__ gcur) {
  __shared__ int cnt[NBUCK], gbase[NBUCK], lcur[NBUCK];
  int t = threadIdx.x;
  for (int i = t; i < NBUCK; i += 256) cnt[i] = 0;
  __syncthreads();
  int base = blockIdx.x * EPB;
  int s[16], d[16];
#pragma unroll
  for (int j = 0; j < 16; ++j) {
    int e = base + j * 256 + t;  // coalesced
    if (e < EDGES) {
      s[j] = src[e];
      d[j] = dst[e];
      atomicAdd(&cnt[d[j] >> 9], 1);
    } else {
      d[j] = -1;
    }
  }
  __syncthreads();
  for (int i = t; i < NBUCK; i += 256) {
    int c = cnt[i];
    gbase[i] = c ? atomicAdd(&gcur[i], c) : 0;  // ONE global atomic per (block,bucket)
    lcur[i] = 0;
  }
  __syncthreads();
#pragma unroll
  for (int j = 0; j < 16; ++j) {
    if (d[j] >= 0) {
      int bk = d[j] >> 9;
      int lp = atomicAdd(&lcur[bk], 1);  // LDS atomic (cheap)
      int pos = gbase[bk] + lp;
      if (pos < BCAP2) bins[bk * BCAP2 + pos] = s[j] | ((d[j] & 511) << 17);
    }
  }
}

// ---------- phase A2: per-bucket LDS histogram -> deg + dinv ----------
__global__ __launch_bounds__(256) void k_hist(const int* __restrict__ bins,
                                              const int* __restrict__ gcur,
                                              int* __restrict__ deg,
                                              float* __restrict__ dinv) {
  __shared__ int cnt[512];
  int b = blockIdx.x, t = threadIdx.x;
  cnt[t] = 0; cnt[t + 256] = 0;
  __syncthreads();
  int c = gcur[b]; if (c > BCAP2) c = BCAP2;
  const int* bp = &bins[b * BCAP2];
  for (int i = t; i < c; i += 256)
    atomicAdd(&cnt[(bp[i] >> 17) & 511], 1);
  __syncthreads();
#pragma unroll
  for (int k = 0; k < 2; ++k) {
    int n = b * 512 + t + k * 256;
    if (n < NODES) {
      int cc = cnt[t + k * 256];
      deg[n] = cc;
      dinv[n] = rsqrtf((float)cc + 1.0f);
    }
  }
}

// ---------- scan (3-phase exclusive prefix over deg) ----------
__global__ void k_scan1(const int* __restrict__ deg, int* __restrict__ part) {
  __shared__ int sw[4];
  int b = blockIdx.x, t = threadIdx.x;
  int base = b * SCAN_CHUNK;
  int s = 0;
#pragma unroll
  for (int j = 0; j < 4; ++j) {
    int i = base + t * 4 + j;
    if (i < NODES) s += deg[i];
  }
  for (int o = 32; o > 0; o >>= 1) s += __shfl_xor(s, o, 64);
  if ((t & 63) == 0) sw[t >> 6] = s;
  __syncthreads();
  if (t == 0) part[b] = sw[0] + sw[1] + sw[2] + sw[3];
}

__global__ void k_scan2(int* part, int nb) {
  __shared__ int sm[128];
  int t = threadIdx.x;
  int v = (t < nb) ? part[t] : 0;
  sm[t] = v;
  __syncthreads();
  for (int o = 1; o < 128; o <<= 1) {
    int u = (t >= o) ? sm[t - o] : 0;
    __syncthreads();
    sm[t] += u;
    __syncthreads();
  }
  if (t < nb) part[t] = sm[t] - v;  // exclusive
}

__global__ void k_scan3(const int* __restrict__ deg, const int* __restrict__ part,
                        int* __restrict__ rowptr) {
  __shared__ int wtot[4];
  int b = blockIdx.x, t = threadIdx.x;
  int lane = t & 63, wid = t >> 6;
  int base = b * SCAN_CHUNK;
  int d[4];
  int s = 0;
#pragma unroll
  for (int j = 0; j < 4; ++j) {
    int i = base + t * 4 + j;
    d[j] = (i < NODES) ? deg[i] : 0;
    s += d[j];
  }
  int inc = s;
#pragma unroll
  for (int o = 1; o < 64; o <<= 1) {
    int u = __shfl_up(inc, o, 64);
    if (lane >= o) inc += u;
  }
  if (lane == 63) wtot[wid] = inc;
  __syncthreads();
  int wpre = 0;
  for (int w = 0; w < wid; ++w) wpre += wtot[w];
  int off = part[b] + wpre + inc - s;
#pragma unroll
  for (int j = 0; j < 4; ++j) {
    int i = base + t * 4 + j;
    if (i < NODES) { rowptr[i] = off; off += d[j]; }
  }
  if (b == 0 && t == 0) rowptr[NODES] = EDGES;
}

// ---------- phase B: fill csr; block owns one 512-node bucket; LDS cursors ----------
__global__ __launch_bounds__(256) void k_fillb(const int* __restrict__ bins,
                                               const int* __restrict__ gcur,
                                               const int* __restrict__ rowptr,
                                               int* __restrict__ csr) {
  __shared__ int cur[512];
  int b = blockIdx.x, t = threadIdx.x;
#pragma unroll
  for (int k = 0; k < 2; ++k) {
    int n = b * 512 + t + k * 256;
    cur[t + k * 256] = (n < NODES) ? rowptr[n] : 0;
  }
  __syncthreads();
  int c = gcur[b]; if (c > BCAP2) c = BCAP2;
  const int* bp = &bins[b * BCAP2];
  for (int i = t; i < c; i += 256) {
    int pk = bp[i];
    int p = atomicAdd(&cur[(pk >> 17) & 511], 1);
    csr[p] = pk & 0x1FFFF;
  }
}

// ---------- GEMM (fp32 acts): [N,K] fp32 @ [K,64] -> hs = (x@W)*dinv[row], bf16 ----------
template <int K>
__global__ __launch_bounds__(256) void k_gemm_f32(const float* __restrict__ x,
                                                  const float* __restrict__ W,
                                                  const float* __restrict__ dinv,
                                                  short* __restrict__ hs) {
  constexpr int KP = K + 8;
  __shared__ short wt[64 * KP];
  for (int idx = threadIdx.x; idx < K * 64; idx += 256) {
    int k = idx >> 6, n = idx & 63;
    wt[n * KP + k] = f2bf(W[idx]);  // W^T staged as bf16
  }
  __syncthreads();
  int wid = threadIdx.x >> 6, lane = threadIdx.x & 63;
  int tile = blockIdx.x * 4 + wid;
  if (tile * 16 >= NODES) return;
  int m = lane & 15, q = lane >> 4;

  short8 bfr[4][K / 32];
#pragma unroll
  for (int ct = 0; ct < 4; ++ct)
#pragma unroll
    for (int ks = 0; ks < K / 32; ++ks)
      bfr[ct][ks] = *reinterpret_cast<const short8*>(&wt[(ct * 16 + m) * KP + ks * 32 + q * 8]);

  floatx4 acc[4];
#pragma unroll
  for (int ct = 0; ct < 4; ++ct) acc[ct] = {0.f, 0.f, 0.f, 0.f};
  int r0 = tile * 16;
#pragma unroll
  for (int ks = 0; ks < K / 32; ++ks) {
    const float* xp = &x[(size_t)(r0 + m) * K + ks * 32 + q * 8];
    floatx4 a0 = *reinterpret_cast<const floatx4*>(xp);
    floatx4 a1 = *reinterpret_cast<const floatx4*>(xp + 4);
    short8 af;
#pragma unroll
    for (int j = 0; j < 4; ++j) { af[j] = f2bf(a0[j]); af[4 + j] = f2bf(a1[j]); }
#pragma unroll
    for (int ct = 0; ct < 4; ++ct)
      acc[ct] = __builtin_amdgcn_mfma_f32_16x16x32_bf16(af, bfr[ct][ks], acc[ct], 0, 0, 0);
  }
  // C/D: col = lane&15, row = (lane>>4)*4 + reg   [measured m89/m91]
  float dv[4];
#pragma unroll
  for (int r = 0; r < 4; ++r) dv[r] = dinv[r0 + q * 4 + r];
#pragma unroll
  for (int ct = 0; ct < 4; ++ct)
#pragma unroll
    for (int r = 0; r < 4; ++r) {
      int row = r0 + q * 4 + r, col = ct * 16 + m;
      hs[row * 64 + col] = f2bf(acc[ct][r] * dv[r]);
    }
}

// ---------- GEMM (bf16 acts): [N,64] bf16 @ [64,64] -> hs bf16 (dinv-prescaled) ----------
__global__ __launch_bounds__(256) void k_gemm_bf(const short* __restrict__ x,
                                                 const float* __restrict__ W,
                                                 const float* __restrict__ dinv,
                                                 short* __restrict__ hs) {
  constexpr int K = 64, KP = K + 8;
  __shared__ short wt[64 * KP];
  for (int idx = threadIdx.x; idx < K * 64; idx += 256) {
    int k = idx >> 6, n = idx & 63;
    wt[n * KP + k] = f2bf(W[idx]);
  }
  __syncthreads();
  int wid = threadIdx.x >> 6, lane = threadIdx.x & 63;
  int tile = blockIdx.x * 4 + wid;
  if (tile * 16 >= NODES) return;
  int m = lane & 15, q = lane >> 4;

  short8 bfr[4][2];
#pragma unroll
  for (int ct = 0; ct < 4; ++ct)
#pragma unroll
    for (int ks = 0; ks < 2; ++ks)
      bfr[ct][ks] = *reinterpret_cast<const short8*>(&wt[(ct * 16 + m) * KP + ks * 32 + q * 8]);

  floatx4 acc[4];
#pragma unroll
  for (int ct = 0; ct < 4; ++ct) acc[ct] = {0.f, 0.f, 0.f, 0.f};
  int r0 = tile * 16;
#pragma unroll
  for (int ks = 0; ks < 2; ++ks) {
    short8 af = *reinterpret_cast<const short8*>(&x[(size_t)(r0 + m) * K + ks * 32 + q * 8]);
#pragma unroll
    for (int ct = 0; ct < 4; ++ct)
      acc[ct] = __builtin_amdgcn_mfma_f32_16x16x32_bf16(af, bfr[ct][ks], acc[ct], 0, 0, 0);
  }
  float dv[4];
#pragma unroll
  for (int r = 0; r < 4; ++r) dv[r] = dinv[r0 + q * 4 + r];
#pragma unroll
  for (int ct = 0; ct < 4; ++ct)
#pragma unroll
    for (int r = 0; r < 4; ++r) {
      int row = r0 + q * 4 + r, col = ct * 16 + m;
      hs[row * 64 + col] = f2bf(acc[ct][r] * dv[r]);
    }
}

// ---------- fused aggregate + bias + LN + GELU (+ head) ----------
// 8 nodes per wave: 8-lane group per node, lane holds 8 features as uv4 (16B gathers).
// hs dinv-prescaled: pre = dinv[n] * (hs[n] + sum hs[src]) + bias
template <int FINAL>
__global__ __launch_bounds__(256) void k_agg(const short* __restrict__ hs,
                                             const float* __restrict__ dinv,
                                             const int* __restrict__ rowptr,
                                             const int* __restrict__ csr,
                                             const float* __restrict__ bias,
                                             const float* __restrict__ gam,
                                             const float* __restrict__ bet,
                                             const float* __restrict__ Wh,
                                             const float* __restrict__ bh,
                                             void* __restrict__ out) {
  const uv4* hsv = (const uv4*)hs;
  int lane = threadIdx.x & 63, wid = threadIdx.x >> 6;
  int g = lane >> 3, q = lane & 7;
  int n = blockIdx.x * 32 + wid * 8 + g;   // 32 nodes per block (grid 3125 exact)
  int e0 = rowptr[n], e1 = rowptr[n + 1];
  float dn = dinv[n];
  uv4 sv = hsv[(size_t)n * 8 + q];          // self row, features q*8..q*8+7
  float acc[8];
#pragma unroll
  for (int w = 0; w < 4; ++w) { acc[2 * w] = bflo(sv[w]); acc[2 * w + 1] = bfhi(sv[w]); }

  int srcb = lane & 0x38;                   // group base lane
  for (int base = e0; base < e1; base += 8) {
    int cnt = e1 - base;                    // >= 1 inside loop
    if (cnt > 8) cnt = 8;
    int a = base + (q < cnt ? q : 0);       // clamp: always valid in-row index
    int sidx = csr[a];
    int s[8];
#pragma unroll
    for (int j = 0; j < 8; ++j) s[j] = __shfl(sidx, srcb | j, 64);  // 1 bpermute serves 8 edges
    uv4 v[8];
#pragma unroll
    for (int j = 0; j < 8; ++j) v[j] = hsv[(size_t)s[j] * 8 + q];   // 1 inst gathers 8 rows
    if (cnt == 8) {                          // fast path: no per-j masking
#pragma unroll
      for (int j = 0; j < 8; ++j)
#pragma unroll
        for (int w = 0; w < 4; ++w) { acc[2 * w] += bflo(v[j][w]); acc[2 * w + 1] += bfhi(v[j][w]); }
    } else {                                 // tail batch: j >= cnt are dups of s[0], masked off
#pragma unroll
      for (int j = 0; j < 8; ++j)
        if (j < cnt)
#pragma unroll
          for (int w = 0; w < 4; ++w) { acc[2 * w] += bflo(v[j][w]); acc[2 * w + 1] += bfhi(v[j][w]); }
    }
  }

  const floatx4* bi4 = (const floatx4*)bias;
  floatx4 b0 = bi4[q * 2], b1 = bi4[q * 2 + 1];
#pragma unroll
  for (int f = 0; f < 4; ++f) { acc[f] = acc[f] * dn + b0[f]; acc[f + 4] = acc[f + 4] * dn + b1[f]; }

  float lsum = 0.f;
#pragma unroll
  for (int f = 0; f < 8; ++f) lsum += acc[f];
  float mu = gsum8(lsum) * (1.0f / 64.0f);
  float d[8], lvar = 0.f;
#pragma unroll
  for (int f = 0; f < 8; ++f) { d[f] = acc[f] - mu; lvar += d[f] * d[f]; }
  float rs = rsqrtf(gsum8(lvar) * (1.0f / 64.0f) + 1e-5f);
  const floatx4* gm4 = (const floatx4*)gam;
  const floatx4* bt4 = (const floatx4*)bet;
  floatx4 g0 = gm4[q * 2], g1 = gm4[q * 2 + 1];
  floatx4 t0 = bt4[q * 2], t1 = bt4[q * 2 + 1];
  float u[8];
#pragma unroll
  for (int f = 0; f < 8; ++f) {
    float gv = (f < 4) ? g0[f] : g1[f - 4];
    float tv = (f < 4) ? t0[f] : t1[f - 4];
    float vv = d[f] * rs * gv + tv;
    u[f] = 0.5f * vv * (1.0f + erff(vv * 0.70710678118654752f));  // exact GELU
  }
  if (FINAL) {
    const floatx4* wh4 = (const floatx4*)Wh;
    floatx4 w0 = wh4[q * 2], w1 = wh4[q * 2 + 1];
    float lp = 0.f;
#pragma unroll
    for (int f = 0; f < 4; ++f) lp += u[f] * w0[f] + u[f + 4] * w1[f];
    float p = gsum8(lp);
    if (q == 0) ((float*)out)[n] = p + bh[0];
  } else {
    uv4 pk;
#pragma unroll
    for (int w = 0; w < 4; ++w)
      pk[w] = (unsigned)(unsigned short)f2bf(u[2 * w]) |
              ((unsigned)(unsigned short)f2bf(u[2 * w + 1]) << 16);
    ((uv4*)out)[(size_t)n * 8 + q] = pk;
  }
}

extern "C" void kernel_launch(void* const* d_in, const int* in_sizes, int n_in,
                              void* d_out, int out_size, void* d_ws, size_t ws_size,
                              hipStream_t stream) {
  const float* x  = (const float*)d_in[0];
  const int* ei   = (const int*)d_in[1];
  const float* W1 = (const float*)d_in[2];
  const float* b1 = (const float*)d_in[3];
  const float* g1 = (const float*)d_in[4];
  const float* be1= (const float*)d_in[5];
  const float* W2 = (const float*)d_in[6];
  const float* b2 = (const float*)d_in[7];
  const float* g2 = (const float*)d_in[8];
  const float* be2= (const float*)d_in[9];
  const float* W3 = (const float*)d_in[10];
  const float* b3 = (const float*)d_in[11];
  const float* g3 = (const float*)d_in[12];
  const float* be3= (const float*)d_in[13];
  const float* Wh = (const float*)d_in[14];
  const float* bh = (const float*)d_in[15];
  const int* srcp = ei;
  const int* dstp = ei + EDGES;

  char* ws = (char*)d_ws;
  size_t off = 0;
  auto take = [&](size_t bytes) {
    char* p = ws + off;
    off = (off + bytes + 255) & ~(size_t)255;
    return p;
  };
  int* deg    = (int*)take((size_t)NODES * 4);
  float* dinv = (float*)take((size_t)NODES * 4);
  int* rowptr = (int*)take((size_t)(NODES + 1) * 4);
  int* part   = (int*)take(512);
  int* csr    = (int*)take((size_t)EDGES * 4);
  short* hs   = (short*)take((size_t)NODES * 64 * 2);   // 12.8 MB
  short* xb   = (short*)take((size_t)NODES * 64 * 2);   // 12.8 MB
  // bins/gcur alias hs/xb: dead before first GEMM writes hs.
  int* bins   = (int*)hs;                                // NBUCK*BCAP2*4 = 9.63 MB
  int* gcur   = (int*)xb;                                // NBUCK*4 = 784 B

  (void)hipMemsetAsync(gcur, 0, (size_t)NBUCK * 4, stream);
  k_bin2<<<(EDGES + EPB - 1) / EPB, 256, 0, stream>>>(srcp, dstp, bins, gcur);
  k_hist<<<NBUCK, 256, 0, stream>>>(bins, gcur, deg, dinv);
  int nb = (NODES + SCAN_CHUNK - 1) / SCAN_CHUNK;  // 98
  k_scan1<<<nb, 256, 0, stream>>>(deg, part);
  k_scan2<<<1, 128, 0, stream>>>(part, nb);
  k_scan3<<<nb, 256, 0, stream>>>(deg, part, rowptr);
  k_fillb<<<NBUCK, 256, 0, stream>>>(bins, gcur, rowptr, csr);

  int gemm_grid = (NODES / 16 + 3) / 4;  // 1563 blocks x 4 waves
  k_gemm_f32<128><<<gemm_grid, 256, 0, stream>>>(x, W1, dinv, hs);
  k_agg<0><<<NODES / 32, 256, 0, stream>>>(hs, dinv, rowptr, csr, b1, g1, be1, nullptr, nullptr, xb);
  k_gemm_bf<<<gemm_grid, 256, 0, stream>>>(xb, W2, dinv, hs);
  k_agg<0><<<NODES / 32, 256, 0, stream>>>(hs, dinv, rowptr, csr, b2, g2, be2, nullptr, nullptr, xb);
  k_gemm_bf<<<gemm_grid, 256, 0, stream>>>(xb, W3, dinv, hs);
  k_agg<1><<<NODES / 32, 256, 0, stream>>>(hs, dinv, rowptr, csr, b3, g3, be3, Wh, bh, d_out);
}

// Round 12
// 292.847 us; speedup vs baseline: 2.7072x; 1.0195x over previous
//
#include <hip/hip_runtime.h>
#include <math.h>

#define NODES 100000
#define EDGES 1600000
#define NBUCK 196     // ceil(NODES/512) dst-range buckets (512 nodes each)
#define BCAP2 12288   // capacity per bucket (mean 8163, +45 sigma slack)
#define EPB 4096      // edges per binning block

typedef __attribute__((ext_vector_type(8))) short short8;
typedef __attribute__((ext_vector_type(4))) float floatx4;
typedef __attribute__((ext_vector_type(4))) unsigned uv4;

// group-of-8 reduction (xor 4,2,1 stays inside an aligned 8-lane group)
__device__ __forceinline__ float gsum8(float x) {
#pragma unroll
  for (int o = 4; o > 0; o >>= 1) x += __shfl_xor(x, o, 64);
  return x;
}

// bf16 <-> fp32 (RNE), no dependence on __hip_bfloat16 internals.
__device__ __forceinline__ short f2bf(float f) {
  union { float f; unsigned u; } v;
  v.f = f;
  unsigned r = 0x7fffu + ((v.u >> 16) & 1u);
  return (short)((v.u + r) >> 16);
}
__device__ __forceinline__ float bflo(unsigned p) {
  union { unsigned u; float f; } v; v.u = p << 16; return v.f;
}
__device__ __forceinline__ float bfhi(unsigned p) {
  union { unsigned u; float f; } v; v.u = p & 0xffff0000u; return v.f;
}

// ---------- phase A: two-pass LDS binning; ~196 global atomics per block ----------
// record = src (17b) | (dst & 511) << 17
__global__ __launch_bounds__(256) void k_bin2(const int* __restrict__ src,
                                              const int* __restrict__ dst,
                                              int* __restrict__ bins,
                                              int* __restrict__ gcur) {
  __shared__ int cnt[NBUCK], gbase[NBUCK], lcur[NBUCK];
  int t = threadIdx.x;
  for (int i = t; i < NBUCK; i += 256) cnt[i] = 0;
  __syncthreads();
  int base = blockIdx.x * EPB;
  int s[16], d[16];
#pragma unroll
  for (int j = 0; j < 16; ++j) {
    int e = base + j * 256 + t;  // coalesced
    if (e < EDGES) {
      s[j] = src[e];
      d[j] = dst[e];
      atomicAdd(&cnt[d[j] >> 9], 1);
    } else {
      d[j] = -1;
    }
  }
  __syncthreads();
  for (int i = t; i < NBUCK; i += 256) {
    int c = cnt[i];
    gbase[i] = c ? atomicAdd(&gcur[i], c) : 0;  // ONE global atomic per (block,bucket)
    lcur[i] = 0;
  }
  __syncthreads();
#pragma unroll
  for (int j = 0; j < 16; ++j) {
    if (d[j] >= 0) {
      int bk = d[j] >> 9;
      int lp = atomicAdd(&lcur[bk], 1);  // LDS atomic (cheap)
      int pos = gbase[bk] + lp;
      if (pos < BCAP2) bins[bk * BCAP2 + pos] = s[j] | ((d[j] & 511) << 17);
    }
  }
}

// ---------- bucket-level exclusive scan (196 elems, 1 block) ----------
__global__ void k_scanb(const int* __restrict__ gcur, int* __restrict__ bbase,
                        int* __restrict__ rowptr) {
  __shared__ int sm[256];
  int t = threadIdx.x;
  int v = 0;
  if (t < NBUCK) { v = gcur[t]; if (v > BCAP2) v = BCAP2; }
  sm[t] = v;
  __syncthreads();
  for (int o = 1; o < 256; o <<= 1) {
    int u = (t >= o) ? sm[t - o] : 0;
    __syncthreads();
    sm[t] += u;
    __syncthreads();
  }
  if (t < NBUCK) bbase[t] = sm[t] - v;  // exclusive
  if (t == NBUCK - 1) {
    bbase[NBUCK] = sm[t];
    rowptr[NODES] = sm[t];              // = EDGES barring (unreachable) overflow
  }
}

// ---------- fused: per-bucket histogram + LDS scan -> rowptr/dinv + csr fill ----------
__global__ __launch_bounds__(256) void k_fillb2(const int* __restrict__ bins,
                                                const int* __restrict__ gcur,
                                                const int* __restrict__ bbase,
                                                int* __restrict__ rowptr,
                                                float* __restrict__ dinv,
                                                int* __restrict__ csr) {
  __shared__ int cnt[512], cur[512], wtot[4];
  int b = blockIdx.x, t = threadIdx.x;
  cnt[t] = 0; cnt[t + 256] = 0;
  __syncthreads();
  int c = gcur[b]; if (c > BCAP2) c = BCAP2;
  const int* bp = &bins[(size_t)b * BCAP2];
  for (int i = t; i < c; i += 256)
    atomicAdd(&cnt[(bp[i] >> 17) & 511], 1);
  __syncthreads();
  // pair-wise exclusive scan over 512 counters with 256 threads
  int a0 = cnt[2 * t], a1 = cnt[2 * t + 1];
  int s = a0 + a1;
  int lane = t & 63, w = t >> 6;
  int inc = s;
#pragma unroll
  for (int o = 1; o < 64; o <<= 1) {
    int u = __shfl_up(inc, o, 64);
    if (lane >= o) inc += u;
  }
  if (lane == 63) wtot[w] = inc;
  __syncthreads();
  int wpre = 0;
  for (int ww = 0; ww < w; ++ww) wpre += wtot[ww];
  int base = bbase[b];
  int r0 = base + wpre + inc - s;      // exclusive offset of element 2t
  int r1 = r0 + a0;
  int n0 = b * 512 + 2 * t, n1 = n0 + 1;
  if (n0 < NODES) { rowptr[n0] = r0; dinv[n0] = rsqrtf((float)a0 + 1.0f); }
  if (n1 < NODES) { rowptr[n1] = r1; dinv[n1] = rsqrtf((float)a1 + 1.0f); }
  cur[2 * t] = r0; cur[2 * t + 1] = r1;
  __syncthreads();
  for (int i = t; i < c; i += 256) {
    int pk = bp[i];
    int p = atomicAdd(&cur[(pk >> 17) & 511], 1);
    csr[p] = pk & 0x1FFFF;
  }
}

// ---------- GEMM (fp32 acts): [N,K] fp32 @ [K,64] -> hs = (x@W)*dinv[row], bf16 ----------
template <int K>
__global__ __launch_bounds__(256) void k_gemm_f32(const float* __restrict__ x,
                                                  const float* __restrict__ W,
                                                  const float* __restrict__ dinv,
                                                  short* __restrict__ hs) {
  constexpr int KP = K + 8;
  __shared__ short wt[64 * KP];
  for (int idx = threadIdx.x; idx < K * 64; idx += 256) {
    int k = idx >> 6, n = idx & 63;
    wt[n * KP + k] = f2bf(W[idx]);  // W^T staged as bf16
  }
  __syncthreads();
  int wid = threadIdx.x >> 6, lane = threadIdx.x & 63;
  int tile = blockIdx.x * 4 + wid;
  if (tile * 16 >= NODES) return;
  int m = lane & 15, q = lane >> 4;

  short8 bfr[4][K / 32];
#pragma unroll
  for (int ct = 0; ct < 4; ++ct)
#pragma unroll
    for (int ks = 0; ks < K / 32; ++ks)
      bfr[ct][ks] = *reinterpret_cast<const short8*>(&wt[(ct * 16 + m) * KP + ks * 32 + q * 8]);

  floatx4 acc[4];
#pragma unroll
  for (int ct = 0; ct < 4; ++ct) acc[ct] = {0.f, 0.f, 0.f, 0.f};
  int r0 = tile * 16;
#pragma unroll
  for (int ks = 0; ks < K / 32; ++ks) {
    const float* xp = &x[(size_t)(r0 + m) * K + ks * 32 + q * 8];
    floatx4 a0 = *reinterpret_cast<const floatx4*>(xp);
    floatx4 a1 = *reinterpret_cast<const floatx4*>(xp + 4);
    short8 af;
#pragma unroll
    for (int j = 0; j < 4; ++j) { af[j] = f2bf(a0[j]); af[4 + j] = f2bf(a1[j]); }
#pragma unroll
    for (int ct = 0; ct < 4; ++ct)
      acc[ct] = __builtin_amdgcn_mfma_f32_16x16x32_bf16(af, bfr[ct][ks], acc[ct], 0, 0, 0);
  }
  // C/D: col = lane&15, row = (lane>>4)*4 + reg   [measured m89/m91]
  float dv[4];
#pragma unroll
  for (int r = 0; r < 4; ++r) dv[r] = dinv[r0 + q * 4 + r];
#pragma unroll
  for (int ct = 0; ct < 4; ++ct)
#pragma unroll
    for (int r = 0; r < 4; ++r) {
      int row = r0 + q * 4 + r, col = ct * 16 + m;
      hs[row * 64 + col] = f2bf(acc[ct][r] * dv[r]);
    }
}

// ---------- GEMM (bf16 acts): [N,64] bf16 @ [64,64] -> hs bf16 (dinv-prescaled) ----------
__global__ __launch_bounds__(256) void k_gemm_bf(const short* __restrict__ x,
                                                 const float* __restrict__ W,
                                                 const float* __restrict__ dinv,
                                                 short* __restrict__ hs) {
  constexpr int K = 64, KP = K + 8;
  __shared__ short wt[64 * KP];
  for (int idx = threadIdx.x; idx < K * 64; idx += 256) {
    int k = idx >> 6, n = idx & 63;
    wt[n * KP + k] = f2bf(W[idx]);
  }
  __syncthreads();
  int wid = threadIdx.x >> 6, lane = threadIdx.x & 63;
  int tile = blockIdx.x * 4 + wid;
  if (tile * 16 >= NODES) return;
  int m = lane & 15, q = lane >> 4;

  short8 bfr[4][2];
#pragma unroll
  for (int ct = 0; ct < 4; ++ct)
#pragma unroll
    for (int ks = 0; ks < 2; ++ks)
      bfr[ct][ks] = *reinterpret_cast<const short8*>(&wt[(ct * 16 + m) * KP + ks * 32 + q * 8]);

  floatx4 acc[4];
#pragma unroll
  for (int ct = 0; ct < 4; ++ct) acc[ct] = {0.f, 0.f, 0.f, 0.f};
  int r0 = tile * 16;
#pragma unroll
  for (int ks = 0; ks < 2; ++ks) {
    short8 af = *reinterpret_cast<const short8*>(&x[(size_t)(r0 + m) * K + ks * 32 + q * 8]);
#pragma unroll
    for (int ct = 0; ct < 4; ++ct)
      acc[ct] = __builtin_amdgcn_mfma_f32_16x16x32_bf16(af, bfr[ct][ks], acc[ct], 0, 0, 0);
  }
  float dv[4];
#pragma unroll
  for (int r = 0; r < 4; ++r) dv[r] = dinv[r0 + q * 4 + r];
#pragma unroll
  for (int ct = 0; ct < 4; ++ct)
#pragma unroll
    for (int r = 0; r < 4; ++r) {
      int row = r0 + q * 4 + r, col = ct * 16 + m;
      hs[row * 64 + col] = f2bf(acc[ct][r] * dv[r]);
    }
}

// ---------- fused aggregate + bias + LN + GELU (+ head) ----------
// 8 nodes per wave: 8-lane group per node, lane holds 8 features as uv4 (16B gathers).
// hs dinv-prescaled: pre = dinv[n] * (hs[n] + sum hs[src]) + bias
template <int FINAL>
__global__ __launch_bounds__(256) void k_agg(const short* __restrict__ hs,
                                             const float* __restrict__ dinv,
                                             const int* __restrict__ rowptr,
                                             const int* __restrict__ csr,
                                             const float* __restrict__ bias,
                                             const float* __restrict__ gam,
                                             const float* __restrict__ bet,
                                             const float* __restrict__ Wh,
                                             const float* __restrict__ bh,
                                             void* __restrict__ out) {
  const uv4* hsv = (const uv4*)hs;
  int lane = threadIdx.x & 63, wid = threadIdx.x >> 6;
  int g = lane >> 3, q = lane & 7;
  int n = blockIdx.x * 32 + wid * 8 + g;   // 32 nodes per block (grid 3125 exact)
  int e0 = rowptr[n], e1 = rowptr[n + 1];
  float dn = dinv[n];
  uv4 sv = hsv[(size_t)n * 8 + q];          // self row, features q*8..q*8+7
  float acc[8];
#pragma unroll
  for (int w = 0; w < 4; ++w) { acc[2 * w] = bflo(sv[w]); acc[2 * w + 1] = bfhi(sv[w]); }

  int srcb = lane & 0x38;                   // group base lane
  for (int base = e0; base < e1; base += 8) {
    int cnt = e1 - base;
    if (cnt > 8) cnt = 8;
    int a = base + (q < cnt ? q : 0);       // clamp: always valid in-row index
    int sidx = csr[a];
    int s[8];
#pragma unroll
    for (int j = 0; j < 8; ++j) s[j] = __shfl(sidx, srcb | j, 64);  // 1 bpermute serves 8 edges
    uv4 v[8];
#pragma unroll
    for (int j = 0; j < 8; ++j) v[j] = hsv[(size_t)s[j] * 8 + q];   // 1 inst gathers 8 rows
    if (cnt == 8) {                          // fast path: no per-j masking
#pragma unroll
      for (int j = 0; j < 8; ++j)
#pragma unroll
        for (int w = 0; w < 4; ++w) { acc[2 * w] += bflo(v[j][w]); acc[2 * w + 1] += bfhi(v[j][w]); }
    } else {                                 // tail batch
#pragma unroll
      for (int j = 0; j < 8; ++j)
        if (j < cnt)
#pragma unroll
          for (int w = 0; w < 4; ++w) { acc[2 * w] += bflo(v[j][w]); acc[2 * w + 1] += bfhi(v[j][w]); }
    }
  }

  const floatx4* bi4 = (const floatx4*)bias;
  floatx4 b0 = bi4[q * 2], b1 = bi4[q * 2 + 1];
#pragma unroll
  for (int f = 0; f < 4; ++f) { acc[f] = acc[f] * dn + b0[f]; acc[f + 4] = acc[f + 4] * dn + b1[f]; }

  float lsum = 0.f;
#pragma unroll
  for (int f = 0; f < 8; ++f) lsum += acc[f];
  float mu = gsum8(lsum) * (1.0f / 64.0f);
  float d[8], lvar = 0.f;
#pragma unroll
  for (int f = 0; f < 8; ++f) { d[f] = acc[f] - mu; lvar += d[f] * d[f]; }
  float rs = rsqrtf(gsum8(lvar) * (1.0f / 64.0f) + 1e-5f);
  const floatx4* gm4 = (const floatx4*)gam;
  const floatx4* bt4 = (const floatx4*)bet;
  floatx4 g0 = gm4[q * 2], g1 = gm4[q * 2 + 1];
  floatx4 t0 = bt4[q * 2], t1 = bt4[q * 2 + 1];
  float u[8];
#pragma unroll
  for (int f = 0; f < 8; ++f) {
    float gv = (f < 4) ? g0[f] : g1[f - 4];
    float tv = (f < 4) ? t0[f] : t1[f - 4];
    float vv = d[f] * rs * gv + tv;
    u[f] = 0.5f * vv * (1.0f + erff(vv * 0.70710678118654752f));  // exact GELU
  }
  if (FINAL) {
    const floatx4* wh4 = (const floatx4*)Wh;
    floatx4 w0 = wh4[q * 2], w1 = wh4[q * 2 + 1];
    float lp = 0.f;
#pragma unroll
    for (int f = 0; f < 4; ++f) lp += u[f] * w0[f] + u[f + 4] * w1[f];
    float p = gsum8(lp);
    if (q == 0) ((float*)out)[n] = p + bh[0];
  } else {
    uv4 pk;
#pragma unroll
    for (int w = 0; w < 4; ++w)
      pk[w] = (unsigned)(unsigned short)f2bf(u[2 * w]) |
              ((unsigned)(unsigned short)f2bf(u[2 * w + 1]) << 16);
    ((uv4*)out)[(size_t)n * 8 + q] = pk;
  }
}

extern "C" void kernel_launch(void* const* d_in, const int* in_sizes, int n_in,
                              void* d_out, int out_size, void* d_ws, size_t ws_size,
                              hipStream_t stream) {
  const float* x  = (const float*)d_in[0];
  const int* ei   = (const int*)d_in[1];
  const float* W1 = (const float*)d_in[2];
  const float* b1 = (const float*)d_in[3];
  const float* g1 = (const float*)d_in[4];
  const float* be1= (const float*)d_in[5];
  const float* W2 = (const float*)d_in[6];
  const float* b2 = (const float*)d_in[7];
  const float* g2 = (const float*)d_in[8];
  const float* be2= (const float*)d_in[9];
  const float* W3 = (const float*)d_in[10];
  const float* b3 = (const float*)d_in[11];
  const float* g3 = (const float*)d_in[12];
  const float* be3= (const float*)d_in[13];
  const float* Wh = (const float*)d_in[14];
  const float* bh = (const float*)d_in[15];
  const int* srcp = ei;
  const int* dstp = ei + EDGES;

  char* ws = (char*)d_ws;
  size_t off = 0;
  auto take = [&](size_t bytes) {
    char* p = ws + off;
    off = (off + bytes + 255) & ~(size_t)255;
    return p;
  };
  float* dinv = (float*)take((size_t)NODES * 4);
  int* rowptr = (int*)take((size_t)(NODES + 1) * 4);
  int* bbase  = (int*)take((size_t)(NBUCK + 1) * 4);
  int* csr    = (int*)take((size_t)EDGES * 4);
  short* hs   = (short*)take((size_t)NODES * 64 * 2);   // 12.8 MB
  short* xb   = (short*)take((size_t)NODES * 64 * 2);   // 12.8 MB
  // bins/gcur alias hs/xb: dead before first GEMM writes hs.
  int* bins   = (int*)hs;                                // NBUCK*BCAP2*4 = 9.63 MB
  int* gcur   = (int*)xb;                                // NBUCK*4 = 784 B

  (void)hipMemsetAsync(gcur, 0, (size_t)NBUCK * 4, stream);
  k_bin2<<<(EDGES + EPB - 1) / EPB, 256, 0, stream>>>(srcp, dstp, bins, gcur);
  k_scanb<<<1, 256, 0, stream>>>(gcur, bbase, rowptr);
  k_fillb2<<<NBUCK, 256, 0, stream>>>(bins, gcur, bbase, rowptr, dinv, csr);

  int gemm_grid = (NODES / 16 + 3) / 4;  // 1563 blocks x 4 waves
  k_gemm_f32<128><<<gemm_grid, 256, 0, stream>>>(x, W1, dinv, hs);
  k_agg<0><<<NODES / 32, 256, 0, stream>>>(hs, dinv, rowptr, csr, b1, g1, be1, nullptr, nullptr, xb);
  k_gemm_bf<<<gemm_grid, 256, 0, stream>>>(xb, W2, dinv, hs);
  k_agg<0><<<NODES / 32, 256, 0, stream>>>(hs, dinv, rowptr, csr, b2, g2, be2, nullptr, nullptr, xb);
  k_gemm_bf<<<gemm_grid, 256, 0, stream>>>(xb, W3, dinv, hs);
  k_agg<1><<<NODES / 32, 256, 0, stream>>>(hs, dinv, rowptr, csr, b3, g3, be3, Wh, bh, d_out);
}

// Round 13
// 280.383 us; speedup vs baseline: 2.8275x; 1.0445x over previous
//
#include <hip/hip_runtime.h>
#include <math.h>

#define NODES 100000
#define EDGES 1600000
#define NBUCK 196     // ceil(NODES/512) dst-range buckets (512 nodes each)
#define BCAP2 12288   // capacity per bucket (mean 8163, +45 sigma slack)
#define EPB 4096      // edges per binning block

typedef __attribute__((ext_vector_type(8))) short short8;
typedef __attribute__((ext_vector_type(4))) float floatx4;
typedef __attribute__((ext_vector_type(4))) unsigned uv4;

// group-of-8 reduction (xor 4,2,1 stays inside an aligned 8-lane group)
__device__ __forceinline__ float gsum8(float x) {
#pragma unroll
  for (int o = 4; o > 0; o >>= 1) x += __shfl_xor(x, o, 64);
  return x;
}

// bf16 <-> fp32 (RNE), no dependence on __hip_bfloat16 internals.
__device__ __forceinline__ short f2bf(float f) {
  union { float f; unsigned u; } v;
  v.f = f;
  unsigned r = 0x7fffu + ((v.u >> 16) & 1u);
  return (short)((v.u + r) >> 16);
}
__device__ __forceinline__ float bflo(unsigned p) {
  union { unsigned u; float f; } v; v.u = p << 16; return v.f;
}
__device__ __forceinline__ float bfhi(unsigned p) {
  union { unsigned u; float f; } v; v.u = p & 0xffff0000u; return v.f;
}

// ---------- phase A: two-pass LDS binning; ~196 global atomics per block ----------
// record = src (17b) | (dst & 511) << 17
__global__ __launch_bounds__(256) void k_bin2(const int* __restrict__ src,
                                              const int* __restrict__ dst,
                                              int* __restrict__ bins,
                                              int* __restrict__ gcur) {
  __shared__ int cnt[NBUCK], gbase[NBUCK], lcur[NBUCK];
  int t = threadIdx.x;
  for (int i = t; i < NBUCK; i += 256) cnt[i] = 0;
  __syncthreads();
  int base = blockIdx.x * EPB;
  int s[16], d[16];
#pragma unroll
  for (int j = 0; j < 16; ++j) {
    int e = base + j * 256 + t;  // coalesced
    if (e < EDGES) {
      s[j] = src[e];
      d[j] = dst[e];
      atomicAdd(&cnt[d[j] >> 9], 1);
    } else {
      d[j] = -1;
    }
  }
  __syncthreads();
  for (int i = t; i < NBUCK; i += 256) {
    int c = cnt[i];
    gbase[i] = c ? atomicAdd(&gcur[i], c) : 0;  // ONE global atomic per (block,bucket)
    lcur[i] = 0;
  }
  __syncthreads();
#pragma unroll
  for (int j = 0; j < 16; ++j) {
    if (d[j] >= 0) {
      int bk = d[j] >> 9;
      int lp = atomicAdd(&lcur[bk], 1);  // LDS atomic (cheap)
      int pos = gbase[bk] + lp;
      if (pos < BCAP2) bins[bk * BCAP2 + pos] = s[j] | ((d[j] & 511) << 17);
    }
  }
}

// ---------- fused: bucket scan + per-bucket histogram + rowptr/dinv + csr fill ----------
__global__ __launch_bounds__(256) void k_fillb2(const int* __restrict__ bins,
                                                const int* __restrict__ gcur,
                                                int* __restrict__ rowptr,
                                                float* __restrict__ dinv,
                                                int* __restrict__ csr) {
  __shared__ int bsm[256];
  __shared__ int cnt[512], cur[512], wtot[4];
  int b = blockIdx.x, t = threadIdx.x;
  // local exclusive scan over all 196 bucket counts (every block redoes it — cheap)
  int v = 0;
  if (t < NBUCK) { v = gcur[t]; if (v > BCAP2) v = BCAP2; }
  bsm[t] = v;
  cnt[t] = 0; cnt[t + 256] = 0;
  __syncthreads();
  for (int o = 1; o < 256; o <<= 1) {
    int u = (t >= o) ? bsm[t - o] : 0;
    __syncthreads();
    bsm[t] += u;
    __syncthreads();
  }
  if (b == 0 && t == NBUCK - 1) rowptr[NODES] = bsm[t];  // total placed
  int cb = gcur[b]; if (cb > BCAP2) cb = BCAP2;
  int base = bsm[b] - cb;  // exclusive bucket base
  // histogram of this bucket
  const int* bp = &bins[(size_t)b * BCAP2];
  for (int i = t; i < cb; i += 256)
    atomicAdd(&cnt[(bp[i] >> 17) & 511], 1);
  __syncthreads();
  // pair-wise exclusive scan over 512 counters with 256 threads
  int a0 = cnt[2 * t], a1 = cnt[2 * t + 1];
  int s = a0 + a1;
  int lane = t & 63, w = t >> 6;
  int inc = s;
#pragma unroll
  for (int o = 1; o < 64; o <<= 1) {
    int u = __shfl_up(inc, o, 64);
    if (lane >= o) inc += u;
  }
  if (lane == 63) wtot[w] = inc;
  __syncthreads();
  int wpre = 0;
  for (int ww = 0; ww < w; ++ww) wpre += wtot[ww];
  int r0 = base + wpre + inc - s;      // exclusive offset of element 2t
  int r1 = r0 + a0;
  int n0 = b * 512 + 2 * t, n1 = n0 + 1;
  if (n0 < NODES) { rowptr[n0] = r0; dinv[n0] = rsqrtf((float)a0 + 1.0f); }
  if (n1 < NODES) { rowptr[n1] = r1; dinv[n1] = rsqrtf((float)a1 + 1.0f); }
  cur[2 * t] = r0; cur[2 * t + 1] = r1;
  __syncthreads();
  for (int i = t; i < cb; i += 256) {
    int pk = bp[i];
    int p = atomicAdd(&cur[(pk >> 17) & 511], 1);
    csr[p] = pk & 0x1FFFF;
  }
}

// ---------- GEMM (fp32 acts): [N,K] fp32 @ [K,64] -> hs = (x@W)*dinv[row], bf16 ----------
template <int K>
__global__ __launch_bounds__(256) void k_gemm_f32(const float* __restrict__ x,
                                                  const float* __restrict__ W,
                                                  const float* __restrict__ dinv,
                                                  short* __restrict__ hs) {
  constexpr int KP = K + 8;
  __shared__ __align__(16) short wt[64 * KP];
  for (int idx = threadIdx.x; idx < K * 64; idx += 256) {
    int k = idx >> 6, n = idx & 63;
    wt[n * KP + k] = f2bf(W[idx]);  // W^T staged as bf16
  }
  __syncthreads();
  int wid = threadIdx.x >> 6, lane = threadIdx.x & 63;
  int tile = blockIdx.x * 4 + wid;
  if (tile * 16 >= NODES) return;
  int m = lane & 15, q = lane >> 4;

  short8 bfr[4][K / 32];
#pragma unroll
  for (int ct = 0; ct < 4; ++ct)
#pragma unroll
    for (int ks = 0; ks < K / 32; ++ks)
      bfr[ct][ks] = *reinterpret_cast<const short8*>(&wt[(ct * 16 + m) * KP + ks * 32 + q * 8]);

  floatx4 acc[4];
#pragma unroll
  for (int ct = 0; ct < 4; ++ct) acc[ct] = {0.f, 0.f, 0.f, 0.f};
  int r0 = tile * 16;
#pragma unroll
  for (int ks = 0; ks < K / 32; ++ks) {
    const float* xp = &x[(size_t)(r0 + m) * K + ks * 32 + q * 8];
    floatx4 a0 = *reinterpret_cast<const floatx4*>(xp);
    floatx4 a1 = *reinterpret_cast<const floatx4*>(xp + 4);
    short8 af;
#pragma unroll
    for (int j = 0; j < 4; ++j) { af[j] = f2bf(a0[j]); af[4 + j] = f2bf(a1[j]); }
#pragma unroll
    for (int ct = 0; ct < 4; ++ct)
      acc[ct] = __builtin_amdgcn_mfma_f32_16x16x32_bf16(af, bfr[ct][ks], acc[ct], 0, 0, 0);
  }
  // C/D: col = lane&15, row = (lane>>4)*4 + reg   [measured m89/m91]
  float dv[4];
#pragma unroll
  for (int r = 0; r < 4; ++r) dv[r] = dinv[r0 + q * 4 + r];
#pragma unroll
  for (int ct = 0; ct < 4; ++ct)
#pragma unroll
    for (int r = 0; r < 4; ++r) {
      int row = r0 + q * 4 + r, col = ct * 16 + m;
      hs[row * 64 + col] = f2bf(acc[ct][r] * dv[r]);
    }
}

// ---------- fused aggregate + bias + LN + GELU + next-layer GEMM ----------
// reads hs (dinv-prescaled), writes hsn = dinv ⊙ (u @ W)  [row-scale commute]
__global__ __launch_bounds__(256) void k_aggg(const short* __restrict__ hs,
                                              const float* __restrict__ dinv,
                                              const int* __restrict__ rowptr,
                                              const int* __restrict__ csr,
                                              const float* __restrict__ bias,
                                              const float* __restrict__ gam,
                                              const float* __restrict__ bet,
                                              const float* __restrict__ W,
                                              short* __restrict__ hsn) {
  __shared__ __align__(16) short wt[64 * 72];  // W^T bf16
  __shared__ __align__(16) short ut[32 * 72];  // (dinv*u) tile bf16
  int t = threadIdx.x;
  for (int idx = t; idx < 4096; idx += 256) {
    int k = idx >> 6, n = idx & 63;
    wt[n * 72 + k] = f2bf(W[idx]);
  }
  const uv4* hsv = (const uv4*)hs;
  int lane = t & 63, wid = t >> 6;
  int g = lane >> 3, q = lane & 7;
  int nb0 = blockIdx.x * 32;
  int r = wid * 8 + g;                      // row in 32-node tile
  int n = nb0 + r;                          // grid 3125 exact -> always valid
  int e0 = rowptr[n], e1 = rowptr[n + 1];
  float dn = dinv[n];
  uv4 sv = hsv[(size_t)n * 8 + q];          // self row, features q*8..q*8+7
  float acc[8];
#pragma unroll
  for (int w = 0; w < 4; ++w) { acc[2 * w] = bflo(sv[w]); acc[2 * w + 1] = bfhi(sv[w]); }

  int srcb = lane & 0x38;                   // group base lane
  for (int base = e0; base < e1; base += 8) {
    int cnt = e1 - base;
    if (cnt > 8) cnt = 8;
    int a = base + (q < cnt ? q : 0);       // clamp: always valid in-row index
    int sidx = csr[a];
    int s[8];
#pragma unroll
    for (int j = 0; j < 8; ++j) s[j] = __shfl(sidx, srcb | j, 64);
    uv4 v[8];
#pragma unroll
    for (int j = 0; j < 8; ++j) v[j] = hsv[(size_t)s[j] * 8 + q];
    if (cnt == 8) {
#pragma unroll
      for (int j = 0; j < 8; ++j)
#pragma unroll
        for (int w = 0; w < 4; ++w) { acc[2 * w] += bflo(v[j][w]); acc[2 * w + 1] += bfhi(v[j][w]); }
    } else {
#pragma unroll
      for (int j = 0; j < 8; ++j)
        if (j < cnt)
#pragma unroll
          for (int w = 0; w < 4; ++w) { acc[2 * w] += bflo(v[j][w]); acc[2 * w + 1] += bfhi(v[j][w]); }
    }
  }

  const floatx4* bi4 = (const floatx4*)bias;
  floatx4 b0 = bi4[q * 2], b1 = bi4[q * 2 + 1];
#pragma unroll
  for (int f = 0; f < 4; ++f) { acc[f] = acc[f] * dn + b0[f]; acc[f + 4] = acc[f + 4] * dn + b1[f]; }

  float lsum = 0.f;
#pragma unroll
  for (int f = 0; f < 8; ++f) lsum += acc[f];
  float mu = gsum8(lsum) * (1.0f / 64.0f);
  float d[8], lvar = 0.f;
#pragma unroll
  for (int f = 0; f < 8; ++f) { d[f] = acc[f] - mu; lvar += d[f] * d[f]; }
  float rs = rsqrtf(gsum8(lvar) * (1.0f / 64.0f) + 1e-5f);
  const floatx4* gm4 = (const floatx4*)gam;
  const floatx4* bt4 = (const floatx4*)bet;
  floatx4 g0 = gm4[q * 2], g1 = gm4[q * 2 + 1];
  floatx4 t0 = bt4[q * 2], t1 = bt4[q * 2 + 1];
  short8 us;
#pragma unroll
  for (int f = 0; f < 8; ++f) {
    float gv = (f < 4) ? g0[f] : g1[f - 4];
    float tv = (f < 4) ? t0[f] : t1[f - 4];
    float vv = d[f] * rs * gv + tv;
    float u = 0.5f * vv * (1.0f + erff(vv * 0.70710678118654752f));  // exact GELU
    us[f] = f2bf(u * dn);                   // prescale for next layer (commute)
  }
  *reinterpret_cast<short8*>(&ut[r * 72 + q * 8]) = us;
  __syncthreads();

  // in-block GEMM: 32x64 tile @ W (64x64) -> hsn rows nb0..nb0+31
  int m = lane & 15, q2 = lane >> 4;
  int tile = wid >> 1, cb = (wid & 1) * 2;  // wave -> (row-tile, ct pair)
  short8 bfr[2][2];
#pragma unroll
  for (int ct = 0; ct < 2; ++ct)
#pragma unroll
    for (int ks = 0; ks < 2; ++ks)
      bfr[ct][ks] = *reinterpret_cast<const short8*>(&wt[((cb + ct) * 16 + m) * 72 + ks * 32 + q2 * 8]);
  floatx4 ac[2];
#pragma unroll
  for (int ct = 0; ct < 2; ++ct) ac[ct] = {0.f, 0.f, 0.f, 0.f};
#pragma unroll
  for (int ks = 0; ks < 2; ++ks) {
    short8 af = *reinterpret_cast<const short8*>(&ut[(tile * 16 + m) * 72 + ks * 32 + q2 * 8]);
#pragma unroll
    for (int ct = 0; ct < 2; ++ct)
      ac[ct] = __builtin_amdgcn_mfma_f32_16x16x32_bf16(af, bfr[ct][ks], ac[ct], 0, 0, 0);
  }
#pragma unroll
  for (int ct = 0; ct < 2; ++ct)
#pragma unroll
    for (int rr = 0; rr < 4; ++rr) {
      int row = nb0 + tile * 16 + q2 * 4 + rr, col = (cb + ct) * 16 + m;
      hsn[row * 64 + col] = f2bf(ac[ct][rr]);
    }
}

// ---------- final layer: aggregate + bias + LN + GELU + head ----------
__global__ __launch_bounds__(256) void k_agg_fin(const short* __restrict__ hs,
                                                 const float* __restrict__ dinv,
                                                 const int* __restrict__ rowptr,
                                                 const int* __restrict__ csr,
                                                 const float* __restrict__ bias,
                                                 const float* __restrict__ gam,
                                                 const float* __restrict__ bet,
                                                 const float* __restrict__ Wh,
                                                 const float* __restrict__ bh,
                                                 float* __restrict__ out) {
  const uv4* hsv = (const uv4*)hs;
  int lane = threadIdx.x & 63, wid = threadIdx.x >> 6;
  int g = lane >> 3, q = lane & 7;
  int n = blockIdx.x * 32 + wid * 8 + g;
  int e0 = rowptr[n], e1 = rowptr[n + 1];
  float dn = dinv[n];
  uv4 sv = hsv[(size_t)n * 8 + q];
  float acc[8];
#pragma unroll
  for (int w = 0; w < 4; ++w) { acc[2 * w] = bflo(sv[w]); acc[2 * w + 1] = bfhi(sv[w]); }
  int srcb = lane & 0x38;
  for (int base = e0; base < e1; base += 8) {
    int cnt = e1 - base;
    if (cnt > 8) cnt = 8;
    int a = base + (q < cnt ? q : 0);
    int sidx = csr[a];
    int s[8];
#pragma unroll
    for (int j = 0; j < 8; ++j) s[j] = __shfl(sidx, srcb | j, 64);
    uv4 v[8];
#pragma unroll
    for (int j = 0; j < 8; ++j) v[j] = hsv[(size_t)s[j] * 8 + q];
    if (cnt == 8) {
#pragma unroll
      for (int j = 0; j < 8; ++j)
#pragma unroll
        for (int w = 0; w < 4; ++w) { acc[2 * w] += bflo(v[j][w]); acc[2 * w + 1] += bfhi(v[j][w]); }
    } else {
#pragma unroll
      for (int j = 0; j < 8; ++j)
        if (j < cnt)
#pragma unroll
          for (int w = 0; w < 4; ++w) { acc[2 * w] += bflo(v[j][w]); acc[2 * w + 1] += bfhi(v[j][w]); }
    }
  }
  const floatx4* bi4 = (const floatx4*)bias;
  floatx4 b0 = bi4[q * 2], b1 = bi4[q * 2 + 1];
#pragma unroll
  for (int f = 0; f < 4; ++f) { acc[f] = acc[f] * dn + b0[f]; acc[f + 4] = acc[f + 4] * dn + b1[f]; }
  float lsum = 0.f;
#pragma unroll
  for (int f = 0; f < 8; ++f) lsum += acc[f];
  float mu = gsum8(lsum) * (1.0f / 64.0f);
  float d[8], lvar = 0.f;
#pragma unroll
  for (int f = 0; f < 8; ++f) { d[f] = acc[f] - mu; lvar += d[f] * d[f]; }
  float rs = rsqrtf(gsum8(lvar) * (1.0f / 64.0f) + 1e-5f);
  const floatx4* gm4 = (const floatx4*)gam;
  const floatx4* bt4 = (const floatx4*)bet;
  floatx4 g0 = gm4[q * 2], g1 = gm4[q * 2 + 1];
  floatx4 t0 = bt4[q * 2], t1 = bt4[q * 2 + 1];
  const floatx4* wh4 = (const floatx4*)Wh;
  floatx4 w0 = wh4[q * 2], w1 = wh4[q * 2 + 1];
  float lp = 0.f;
#pragma unroll
  for (int f = 0; f < 8; ++f) {
    float gv = (f < 4) ? g0[f] : g1[f - 4];
    float tv = (f < 4) ? t0[f] : t1[f - 4];
    float wv = (f < 4) ? w0[f] : w1[f - 4];
    float vv = d[f] * rs * gv + tv;
    float u = 0.5f * vv * (1.0f + erff(vv * 0.70710678118654752f));
    lp += u * wv;
  }
  float p = gsum8(lp);
  if (q == 0) out[n] = p + bh[0];
}

extern "C" void kernel_launch(void* const* d_in, const int* in_sizes, int n_in,
                              void* d_out, int out_size, void* d_ws, size_t ws_size,
                              hipStream_t stream) {
  const float* x  = (const float*)d_in[0];
  const int* ei   = (const int*)d_in[1];
  const float* W1 = (const float*)d_in[2];
  const float* b1 = (const float*)d_in[3];
  const float* g1 = (const float*)d_in[4];
  const float* be1= (const float*)d_in[5];
  const float* W2 = (const float*)d_in[6];
  const float* b2 = (const float*)d_in[7];
  const float* g2 = (const float*)d_in[8];
  const float* be2= (const float*)d_in[9];
  const float* W3 = (const float*)d_in[10];
  const float* b3 = (const float*)d_in[11];
  const float* g3 = (const float*)d_in[12];
  const float* be3= (const float*)d_in[13];
  const float* Wh = (const float*)d_in[14];
  const float* bh = (const float*)d_in[15];
  const int* srcp = ei;
  const int* dstp = ei + EDGES;

  char* ws = (char*)d_ws;
  size_t off = 0;
  auto take = [&](size_t bytes) {
    char* p = ws + off;
    off = (off + bytes + 255) & ~(size_t)255;
    return p;
  };
  float* dinv = (float*)take((size_t)NODES * 4);
  int* rowptr = (int*)take((size_t)(NODES + 1) * 4);
  int* csr    = (int*)take((size_t)EDGES * 4);
  short* hs_a = (short*)take((size_t)NODES * 64 * 2);   // 12.8 MB
  short* hs_b = (short*)take((size_t)NODES * 64 * 2);   // 12.8 MB
  // bins/gcur alias hs_a/hs_b: consumed by fillb2 before any GEMM writes hs.
  int* bins   = (int*)hs_a;                              // NBUCK*BCAP2*4 = 9.63 MB
  int* gcur   = (int*)hs_b;                              // NBUCK*4 = 784 B

  (void)hipMemsetAsync(gcur, 0, (size_t)NBUCK * 4, stream);
  k_bin2<<<(EDGES + EPB - 1) / EPB, 256, 0, stream>>>(srcp, dstp, bins, gcur);
  k_fillb2<<<NBUCK, 256, 0, stream>>>(bins, gcur, rowptr, dinv, csr);

  int gemm_grid = (NODES / 16 + 3) / 4;  // 1563 blocks x 4 waves
  k_gemm_f32<128><<<gemm_grid, 256, 0, stream>>>(x, W1, dinv, hs_a);
  k_aggg<<<NODES / 32, 256, 0, stream>>>(hs_a, dinv, rowptr, csr, b1, g1, be1, W2, hs_b);
  k_aggg<<<NODES / 32, 256, 0, stream>>>(hs_b, dinv, rowptr, csr, b2, g2, be2, W3, hs_a);
  k_agg_fin<<<NODES / 32, 256, 0, stream>>>(hs_a, dinv, rowptr, csr, b3, g3, be3, Wh, bh, (float*)d_out);
}